// Round 11
// baseline (356.246 us; speedup 1.0000x reference)
//
#include <hip/hip_runtime.h>
#include <hip/hip_bf16.h>
#include <math.h>

typedef __bf16 bf16;
typedef __bf16 bf16x4 __attribute__((ext_vector_type(4)));
typedef __bf16 bf16x8 __attribute__((ext_vector_type(8)));
typedef float floatx4 __attribute__((ext_vector_type(4)));

#define T_ 2048
#define D_ 768
#define H_ 12
#define HD_ 64
#define FF_ 3072
#define LOG2E 1.44269504f
#define LDP 72   // padded LDS row stride (elems)

__device__ __forceinline__ floatx4 mfma_bf16(bf16x8 a, bf16x8 b, floatx4 c) {
  return __builtin_amdgcn_mfma_f32_16x16x32_bf16(a, b, c, 0, 0, 0);
}

// ---------------------------------------------------------------------------
// Fused prologue: blocks [0,4608) convert 7 fp32 weight mats -> bf16;
// blocks [4608,8704) do attn rmsnorm (row = blk-4608).
// ---------------------------------------------------------------------------
__device__ __forceinline__ void rms_row(const float* __restrict__ x,
                                        const float* __restrict__ wt,
                                        bf16* __restrict__ o, int row, int tid) {
  const long off = (long)row * D_;
  float vals[3];
  float ss = 0.f;
#pragma unroll
  for (int i = 0; i < 3; i++) {
    vals[i] = x[off + tid + i * 256];
    ss += vals[i] * vals[i];
  }
#pragma unroll
  for (int d = 1; d < 64; d <<= 1) ss += __shfl_xor(ss, d);
  __shared__ float wsum[4];
  if ((tid & 63) == 0) wsum[tid >> 6] = ss;
  __syncthreads();
  const float tot = wsum[0] + wsum[1] + wsum[2] + wsum[3];
  const float inv = 1.0f / (sqrtf(tot * (1.0f / 768.0f)) + 1e-6f);
#pragma unroll
  for (int i = 0; i < 3; i++)
    o[off + tid + i * 256] = (bf16)(vals[i] * inv * wt[tid + i * 256]);
}

__global__ __launch_bounds__(256)
void prep_k(const float* __restrict__ wq, const float* __restrict__ wk,
            const float* __restrict__ wv, const float* __restrict__ wo,
            const float* __restrict__ w1, const float* __restrict__ w2,
            const float* __restrict__ w3, bf16* __restrict__ o,
            const float* __restrict__ x, const float* __restrict__ anw,
            bf16* __restrict__ hn) {
  if (blockIdx.x >= 4608) {
    rms_row(x, anw, hn, blockIdx.x - 4608, threadIdx.x);
    return;
  }
  const long i = ((long)blockIdx.x * 256 + threadIdx.x) * 8;
  const float* s;
  if      (i <  589824) s = wq + i;
  else if (i < 1179648) s = wk + (i -  589824);
  else if (i < 1769472) s = wv + (i - 1179648);
  else if (i < 2359296) s = wo + (i - 1769472);
  else if (i < 4718592) s = w1 + (i - 2359296);
  else if (i < 7077888) s = w2 + (i - 4718592);
  else                  s = w3 + (i - 7077888);
  const floatx4 a = *(const floatx4*)s;
  const floatx4 b = *(const floatx4*)(s + 4);
  bf16x8 r;
#pragma unroll
  for (int j = 0; j < 4; j++) { r[j] = (bf16)a[j]; r[4 + j] = (bf16)b[j]; }
  *(bf16x8*)&o[i] = r;
}

// ---------------------------------------------------------------------------
// RMSNorm standalone (ffn norm).
// ---------------------------------------------------------------------------
__global__ __launch_bounds__(256)
void rmsnorm_k(const float* __restrict__ x, const float* __restrict__ wt,
               bf16* __restrict__ o) {
  rms_row(x, wt, o, blockIdx.x, threadIdx.x);
}

// ---------------------------------------------------------------------------
// Fused QKV GEMM, 128x128 tile, BK=64, register-prefetch. Epilogue:
//   widx 0/1 (q,k): RoPE in-register (shfl_xor pair exchange).
//   widx 2   (v)  : store transposed to vt[bh][hd][t] (bf16x4).
// ---------------------------------------------------------------------------
__global__ __launch_bounds__(256)
void gemm_qkv(const bf16* __restrict__ A, const bf16* __restrict__ wq,
              const bf16* __restrict__ wk, const bf16* __restrict__ wv,
              bf16* __restrict__ q, bf16* __restrict__ k, bf16* __restrict__ vt,
              const float* __restrict__ cosb, const float* __restrict__ sinb) {
  const int widx = blockIdx.x / 6;
  const int nb   = blockIdx.x % 6;
  const bf16* W = (widx == 0) ? wq : (widx == 1) ? wk : wv;
  const int m0 = blockIdx.y * 128, n0 = nb * 128;
  const int K = D_;

  __shared__ __align__(16) bf16 As[128 * LDP];
  __shared__ __align__(16) bf16 Ws[128 * LDP];

  const int tid = threadIdx.x;
  const int lane = tid & 63;
  const int wm = tid >> 7;
  const int wn = (tid >> 6) & 1;
  const int fr = lane & 15;
  const int fk = (lane >> 4) * 8;

  floatx4 acc[4][4] = {};

  const int ar = tid >> 3;
  const int ac = (tid & 7) * 8;
  const bf16* Aptr = A + (long)(m0 + ar) * K + ac;
  const bf16* Wptr = W + (long)(n0 + ar) * K + ac;
  const long rstep = (long)32 * K;

  bf16x8 apf[4], wpf[4];
#pragma unroll
  for (int c = 0; c < 4; c++) apf[c] = *(const bf16x8*)(Aptr + c * rstep);
#pragma unroll
  for (int c = 0; c < 4; c++) wpf[c] = *(const bf16x8*)(Wptr + c * rstep);

  const int ns = K >> 6;   // 12
  for (int ks = 0; ks < ns; ks++) {
    __syncthreads();
#pragma unroll
    for (int c = 0; c < 4; c++) *(bf16x8*)&As[(ar + c * 32) * LDP + ac] = apf[c];
#pragma unroll
    for (int c = 0; c < 4; c++) *(bf16x8*)&Ws[(ar + c * 32) * LDP + ac] = wpf[c];
    __syncthreads();
    const long koff = (long)((ks + 1 < ns) ? ks + 1 : ks) * 64;
#pragma unroll
    for (int c = 0; c < 4; c++) apf[c] = *(const bf16x8*)(Aptr + koff + c * rstep);
#pragma unroll
    for (int c = 0; c < 4; c++) wpf[c] = *(const bf16x8*)(Wptr + koff + c * rstep);
#pragma unroll
    for (int kc = 0; kc < 2; kc++) {
      bf16x8 af[4], bfv[4];
#pragma unroll
      for (int i = 0; i < 4; i++) af[i]  = *(const bf16x8*)&As[(wm * 64 + i * 16 + fr) * LDP + kc * 32 + fk];
#pragma unroll
      for (int j = 0; j < 4; j++) bfv[j] = *(const bf16x8*)&Ws[(wn * 64 + j * 16 + fr) * LDP + kc * 32 + fk];
#pragma unroll
      for (int i = 0; i < 4; i++)
#pragma unroll
        for (int j = 0; j < 4; j++)
          acc[i][j] = mfma_bf16(af[i], bfv[j], acc[i][j]);
    }
  }

  const int rb = (lane >> 4) * 4;
  if (widx < 2) {
    bf16* O = (widx == 0) ? q : k;
    const float sgn = (fr & 1) ? 1.f : -1.f;
#pragma unroll
    for (int i = 0; i < 4; i++)
#pragma unroll
      for (int j = 0; j < 4; j++) {
        const int n = n0 + wn * 64 + j * 16 + fr;
        const int d = n & 63;
#pragma unroll
        for (int r = 0; r < 4; r++) {
          const int m = m0 + wm * 64 + i * 16 + rb + r;
          const int pos = m & (T_ - 1);
          const float val = acc[i][j][r];
          const float par = __shfl_xor(val, 1);
          const float cc = cosb[pos * HD_ + d];
          const float ss = sinb[pos * HD_ + d];
          O[(long)m * D_ + n] = (bf16)(val * cc + sgn * par * ss);
        }
      }
  } else {
#pragma unroll
    for (int i = 0; i < 4; i++)
#pragma unroll
      for (int j = 0; j < 4; j++) {
        const int n = n0 + wn * 64 + j * 16 + fr;
        const int m = m0 + wm * 64 + i * 16 + rb;
        const int b = m >> 11;
        const int t = m & (T_ - 1);
        const long row = (long)(b * H_ + (n >> 6)) * HD_ + (n & 63);
        bf16x4 pk;
#pragma unroll
        for (int r = 0; r < 4; r++) pk[r] = (bf16)acc[i][j][r];
        *(bf16x4*)&vt[row * T_ + t] = pk;
      }
  }
}

// ---------------------------------------------------------------------------
// GEMM 128x64 tile for wo (N=768, K=768). 384 blocks, XCD-swizzled.
// Epilogue: f32 C = acc + f32 resid.
// ---------------------------------------------------------------------------
__global__ __launch_bounds__(256)
void gemm_n64(const bf16* __restrict__ A, const bf16* __restrict__ W,
              float* __restrict__ C, const float* __restrict__ resid,
              int N, int K) {
  __shared__ __align__(16) bf16 As[128 * LDP];
  __shared__ __align__(16) bf16 Ws[64 * LDP];

  const int L  = blockIdx.x;
  const int j  = L >> 3;
  const int mb = (L & 7) * 4 + (j / 12);
  const int nb = j % 12;
  const int m0 = mb * 128, n0 = nb * 64;

  const int tid = threadIdx.x;
  const int lane = tid & 63;
  const int wm = tid >> 7;
  const int wn = (tid >> 6) & 1;
  const int fr = lane & 15;
  const int fk = (lane >> 4) * 8;

  floatx4 acc[4][2] = {};

  const int ar = tid >> 3;
  const int ac = (tid & 7) * 8;
  const bf16* Aptr = A + (long)(m0 + ar) * K + ac;
  const bf16* Wptr = W + (long)(n0 + ar) * K + ac;
  const long rstep = (long)32 * K;

  bf16x8 apf[4], wpf[2];
#pragma unroll
  for (int c = 0; c < 4; c++) apf[c] = *(const bf16x8*)(Aptr + c * rstep);
#pragma unroll
  for (int c = 0; c < 2; c++) wpf[c] = *(const bf16x8*)(Wptr + c * rstep);

  const int ns = K >> 6;
  for (int ks = 0; ks < ns; ks++) {
    __syncthreads();
#pragma unroll
    for (int c = 0; c < 4; c++) *(bf16x8*)&As[(ar + c * 32) * LDP + ac] = apf[c];
#pragma unroll
    for (int c = 0; c < 2; c++) *(bf16x8*)&Ws[(ar + c * 32) * LDP + ac] = wpf[c];
    __syncthreads();
    const long koff = (long)((ks + 1 < ns) ? ks + 1 : ks) * 64;
#pragma unroll
    for (int c = 0; c < 4; c++) apf[c] = *(const bf16x8*)(Aptr + koff + c * rstep);
#pragma unroll
    for (int c = 0; c < 2; c++) wpf[c] = *(const bf16x8*)(Wptr + koff + c * rstep);
#pragma unroll
    for (int kc = 0; kc < 2; kc++) {
      bf16x8 af[4], bfv[2];
#pragma unroll
      for (int i = 0; i < 4; i++) af[i]  = *(const bf16x8*)&As[(wm * 64 + i * 16 + fr) * LDP + kc * 32 + fk];
#pragma unroll
      for (int j2 = 0; j2 < 2; j2++) bfv[j2] = *(const bf16x8*)&Ws[(wn * 32 + j2 * 16 + fr) * LDP + kc * 32 + fk];
#pragma unroll
      for (int i = 0; i < 4; i++)
#pragma unroll
        for (int j2 = 0; j2 < 2; j2++)
          acc[i][j2] = mfma_bf16(af[i], bfv[j2], acc[i][j2]);
    }
  }

  const int rb = (lane >> 4) * 4;
#pragma unroll
  for (int i = 0; i < 4; i++)
#pragma unroll
    for (int j2 = 0; j2 < 2; j2++) {
      const int n = n0 + wn * 32 + j2 * 16 + fr;
#pragma unroll
      for (int r = 0; r < 4; r++) {
        const int m = m0 + wm * 64 + i * 16 + rb + r;
        const long idx = (long)m * N + n;
        C[idx] = acc[i][j2][r] + resid[idx];
      }
    }
}

// ---------------------------------------------------------------------------
// w3 GEMM, split-K x3: 1152 blocks, each K-third of 3072 (kbase = s*1024,
// 16 steps of 64). s -> p0/p1/p2 (fp32 partials). XCD-swizzled.
// ---------------------------------------------------------------------------
__global__ __launch_bounds__(256)
void gemm_w3sk(const bf16* __restrict__ A, const bf16* __restrict__ W,
               float* __restrict__ p0, float* __restrict__ p1,
               float* __restrict__ p2) {
  __shared__ __align__(16) bf16 As[128 * LDP];
  __shared__ __align__(16) bf16 Ws[64 * LDP];

  const int L  = blockIdx.x;
  const int j  = L >> 3;                  // 0..143
  const int mb = (L & 7) * 4 + (j / 36);
  const int inner = j % 36;
  const int s  = inner / 12;
  const int nb = inner % 12;
  const int m0 = mb * 128, n0 = nb * 64;
  const int K = FF_;
  const int kbase = s * 1024;
  float* C = (s == 0) ? p0 : (s == 1) ? p1 : p2;

  const int tid = threadIdx.x;
  const int lane = tid & 63;
  const int wm = tid >> 7;
  const int wn = (tid >> 6) & 1;
  const int fr = lane & 15;
  const int fk = (lane >> 4) * 8;

  floatx4 acc[4][2] = {};

  const int ar = tid >> 3;
  const int ac = (tid & 7) * 8;
  const bf16* Aptr = A + (long)(m0 + ar) * K + kbase + ac;
  const bf16* Wptr = W + (long)(n0 + ar) * K + kbase + ac;
  const long rstep = (long)32 * K;

  bf16x8 apf[4], wpf[2];
#pragma unroll
  for (int c = 0; c < 4; c++) apf[c] = *(const bf16x8*)(Aptr + c * rstep);
#pragma unroll
  for (int c = 0; c < 2; c++) wpf[c] = *(const bf16x8*)(Wptr + c * rstep);

  const int ns = 16;
  for (int ks = 0; ks < ns; ks++) {
    __syncthreads();
#pragma unroll
    for (int c = 0; c < 4; c++) *(bf16x8*)&As[(ar + c * 32) * LDP + ac] = apf[c];
#pragma unroll
    for (int c = 0; c < 2; c++) *(bf16x8*)&Ws[(ar + c * 32) * LDP + ac] = wpf[c];
    __syncthreads();
    const long koff = (long)((ks + 1 < ns) ? ks + 1 : ks) * 64;
#pragma unroll
    for (int c = 0; c < 4; c++) apf[c] = *(const bf16x8*)(Aptr + koff + c * rstep);
#pragma unroll
    for (int c = 0; c < 2; c++) wpf[c] = *(const bf16x8*)(Wptr + koff + c * rstep);
#pragma unroll
    for (int kc = 0; kc < 2; kc++) {
      bf16x8 af[4], bfv[2];
#pragma unroll
      for (int i = 0; i < 4; i++) af[i]  = *(const bf16x8*)&As[(wm * 64 + i * 16 + fr) * LDP + kc * 32 + fk];
#pragma unroll
      for (int j2 = 0; j2 < 2; j2++) bfv[j2] = *(const bf16x8*)&Ws[(wn * 32 + j2 * 16 + fr) * LDP + kc * 32 + fk];
#pragma unroll
      for (int i = 0; i < 4; i++)
#pragma unroll
        for (int j2 = 0; j2 < 2; j2++)
          acc[i][j2] = mfma_bf16(af[i], bfv[j2], acc[i][j2]);
    }
  }

  const int rb = (lane >> 4) * 4;
#pragma unroll
  for (int i = 0; i < 4; i++)
#pragma unroll
    for (int j2 = 0; j2 < 2; j2++) {
      const int n = n0 + wn * 32 + j2 * 16 + fr;
#pragma unroll
      for (int r = 0; r < 4; r++) {
        const int m = m0 + wm * 64 + i * 16 + rb + r;
        C[(long)m * D_ + n] = acc[i][j2][r];
      }
    }
}

// out = p0 + p1 + p2 + xm (fp32), 3.1M elems, 8/thread.
__global__ __launch_bounds__(256)
void comb3_k(const float* __restrict__ p0, const float* __restrict__ p1,
             const float* __restrict__ p2, const float* __restrict__ xm,
             float* __restrict__ out) {
  const long i = ((long)blockIdx.x * 256 + threadIdx.x) * 8;
#pragma unroll
  for (int c = 0; c < 2; c++) {
    const floatx4 a = *(const floatx4*)&p0[i + c * 4];
    const floatx4 b = *(const floatx4*)&p1[i + c * 4];
    const floatx4 e = *(const floatx4*)&p2[i + c * 4];
    const floatx4 d = *(const floatx4*)&xm[i + c * 4];
    floatx4 r;
#pragma unroll
    for (int q = 0; q < 4; q++) r[q] = a[q] + b[q] + e[q] + d[q];
    *(floatx4*)&out[i + c * 4] = r;
  }
}

// ---------------------------------------------------------------------------
// Fused w1/w2 GEMM + silu-mul. 128x128 dual tile; ONLY A staged via LDS
// (18.4 KB). W1/W2 B-fragments loaded DIRECTLY from global (B-frag = 8
// consecutive k at row n = W + n*K + k; per-XCD W slice 1.18 MB L2-resident).
// 768 blocks (32 mb x 24 nb), mb outer per XCD.
// ---------------------------------------------------------------------------
__global__ __launch_bounds__(256)
void gemm_w12(const bf16* __restrict__ A, const bf16* __restrict__ W1,
              const bf16* __restrict__ W2, bf16* __restrict__ G) {
  __shared__ __align__(16) bf16 As[128 * LDP];

  const int L  = blockIdx.x;
  const int j  = L >> 3;                  // 0..95
  const int mb = j / 3;                   // 0..31 (outer per XCD)
  const int nb = (L & 7) * 3 + (j % 3);   // 0..23
  const int m0 = mb * 128, n0 = nb * 128;
  const int K = D_;

  const int tid = threadIdx.x;
  const int lane = tid & 63;
  const int wm = tid >> 7;
  const int wn = (tid >> 6) & 1;
  const int fr = lane & 15;
  const int fk = (lane >> 4) * 8;

  floatx4 acc1[4][4] = {}, acc2[4][4] = {};

  const int ar = tid >> 3;
  const int ac = (tid & 7) * 8;
  const bf16* Aptr = A + (long)(m0 + ar) * K + ac;
  const long rstep = (long)32 * K;

  const bf16* W1p = W1 + (long)(n0 + wn * 64 + fr) * K + fk;
  const bf16* W2p = W2 + (long)(n0 + wn * 64 + fr) * K + fk;
  const long nstep = (long)16 * K;

  bf16x8 apf[4];
#pragma unroll
  for (int c = 0; c < 4; c++) apf[c] = *(const bf16x8*)(Aptr + c * rstep);

  const int ns = K >> 6;   // 12
  for (int ks = 0; ks < ns; ks++) {
    __syncthreads();
#pragma unroll
    for (int c = 0; c < 4; c++) *(bf16x8*)&As[(ar + c * 32) * LDP + ac] = apf[c];
    __syncthreads();
    const long koff = (long)((ks + 1 < ns) ? ks + 1 : ks) * 64;
#pragma unroll
    for (int c = 0; c < 4; c++) apf[c] = *(const bf16x8*)(Aptr + koff + c * rstep);
#pragma unroll
    for (int kc = 0; kc < 2; kc++) {
      const long kof = (long)ks * 64 + kc * 32;
      bf16x8 b1[4], b2[4], af[4];
#pragma unroll
      for (int jj = 0; jj < 4; jj++) b1[jj] = *(const bf16x8*)(W1p + jj * nstep + kof);
#pragma unroll
      for (int jj = 0; jj < 4; jj++) b2[jj] = *(const bf16x8*)(W2p + jj * nstep + kof);
#pragma unroll
      for (int i = 0; i < 4; i++) af[i] = *(const bf16x8*)&As[(wm * 64 + i * 16 + fr) * LDP + kc * 32 + fk];
#pragma unroll
      for (int i = 0; i < 4; i++)
#pragma unroll
        for (int jj = 0; jj < 4; jj++)
          acc1[i][jj] = mfma_bf16(af[i], b1[jj], acc1[i][jj]);
#pragma unroll
      for (int i = 0; i < 4; i++)
#pragma unroll
        for (int jj = 0; jj < 4; jj++)
          acc2[i][jj] = mfma_bf16(af[i], b2[jj], acc2[i][jj]);
    }
  }

  const int rb = (lane >> 4) * 4;
#pragma unroll
  for (int i = 0; i < 4; i++)
#pragma unroll
    for (int jj = 0; jj < 4; jj++) {
      const int n = n0 + wn * 64 + jj * 16 + fr;
#pragma unroll
      for (int r = 0; r < 4; r++) {
        const int m = m0 + wm * 64 + i * 16 + rb + r;
        const float a1 = acc1[i][jj][r];
        const float a2 = acc2[i][jj][r];
        const float s = a1 / (1.f + exp2f(-a1 * LOG2E));
        G[(long)m * FF_ + n] = (bf16)(s * a2);
      }
    }
}

// ---------------------------------------------------------------------------
// Flash attention, split-K over KV. blockIdx = r*24 + bh (XCD-local K/V).
// Register-prefetch of next round's K/V overlaps global latency with compute.
// ---------------------------------------------------------------------------
__global__ __launch_bounds__(256, 4)
void flash_attn(const bf16* __restrict__ q, const bf16* __restrict__ k,
                const bf16* __restrict__ vtg, float* __restrict__ po,
                float* __restrict__ pm, float* __restrict__ pl) {
  const int gid = blockIdx.x;
  const int bh = gid % 24;
  const int r  = gid / 24;
  int qt, c;
  if (r < 8)       { qt = r; c = 0; }
  else if (r < 24) { qt = 8 + ((r - 8) >> 1); c = (r - 8) & 1; }
  else if (r < 48) { const int u = r - 24; const int d = u / 3; qt = 16 + d; c = u - d * 3; }
  else             { const int u = r - 48; qt = 24 + (u >> 2); c = u & 3; }
  const int b  = bh / H_;
  const int h  = bh % H_;
  const int q0 = qt * 64;
  const int tbeg = c * 8;
  const int tend = (tbeg + 7 < qt) ? tbeg + 7 : qt;

  __shared__ __align__(16) bf16 Qs[64][72];
  __shared__ __align__(16) bf16 Ks[64][72];
  __shared__ __align__(16) bf16 Vt[64][72];
  __shared__ __align__(16) bf16 Ps[4][16][72];

  const int tid = threadIdx.x, lane = tid & 63, w = tid >> 6;
  const int fr = lane & 15, quad = lane >> 4, fk = quad * 8;
  const long base = ((long)b * T_) * D_ + h * HD_;
  const long vbase = (long)bh * HD_ * T_;

  const int srow = tid >> 2, scol = (tid & 3) * 16;
  {
    const long g = base + (long)(q0 + srow) * D_ + scol;
    *(bf16x8*)&Qs[srow][scol]     = *(const bf16x8*)&q[g];
    *(bf16x8*)&Qs[srow][scol + 8] = *(const bf16x8*)&q[g + 8];
  }

  const bf16* kgp = k + base + (long)srow * D_ + scol;
  const bf16* vgp = vtg + vbase + (long)srow * T_ + scol;
  bf16x8 kpf0 = *(const bf16x8*)(kgp + (long)tbeg * 64 * D_);
  bf16x8 kpf1 = *(const bf16x8*)(kgp + (long)tbeg * 64 * D_ + 8);
  bf16x8 vpf0 = *(const bf16x8*)(vgp + tbeg * 64);
  bf16x8 vpf1 = *(const bf16x8*)(vgp + tbeg * 64 + 8);

  float m_st = -1e30f, l_st = 0.f;
  floatx4 o[4] = {};
  const float SC = 0.125f * LOG2E;

  for (int t = tbeg; t <= tend; t++) {
    __syncthreads();
    *(bf16x8*)&Ks[srow][scol]     = kpf0;
    *(bf16x8*)&Ks[srow][scol + 8] = kpf1;
    *(bf16x8*)&Vt[srow][scol]     = vpf0;
    *(bf16x8*)&Vt[srow][scol + 8] = vpf1;
    __syncthreads();
    const int tn = (t + 1 <= tend) ? t + 1 : t;
    kpf0 = *(const bf16x8*)(kgp + (long)tn * 64 * D_);
    kpf1 = *(const bf16x8*)(kgp + (long)tn * 64 * D_ + 8);
    vpf0 = *(const bf16x8*)(vgp + tn * 64);
    vpf1 = *(const bf16x8*)(vgp + tn * 64 + 8);

    floatx4 s[4] = {};
#pragma unroll
    for (int kd = 0; kd < 2; kd++) {
      const bf16x8 bq = *(const bf16x8*)&Qs[w * 16 + fr][kd * 32 + fk];
#pragma unroll
      for (int kt = 0; kt < 4; kt++) {
        const bf16x8 ak = *(const bf16x8*)&Ks[kt * 16 + fr][kd * 32 + fk];
        s[kt] = mfma_bf16(ak, bq, s[kt]);
      }
    }

    if (t == qt) {
      const int qloc = w * 16 + fr;
#pragma unroll
      for (int kt = 0; kt < 4; kt++)
#pragma unroll
        for (int r2 = 0; r2 < 4; r2++) {
          const int kvloc = kt * 16 + quad * 4 + r2;
          s[kt][r2] = (kvloc > qloc) ? -1e30f : s[kt][r2] * SC;
        }
    } else {
#pragma unroll
      for (int kt = 0; kt < 4; kt++)
#pragma unroll
        for (int r2 = 0; r2 < 4; r2++) s[kt][r2] *= SC;
    }

    float mx = -1e30f;
#pragma unroll
    for (int kt = 0; kt < 4; kt++)
#pragma unroll
      for (int r2 = 0; r2 < 4; r2++) mx = fmaxf(mx, s[kt][r2]);
    mx = fmaxf(mx, __shfl_xor(mx, 16));
    mx = fmaxf(mx, __shfl_xor(mx, 32));
    const float mnew  = fmaxf(m_st, mx);
    const float alpha = exp2f(m_st - mnew);
    m_st = mnew;
    float rs = 0.f;
#pragma unroll
    for (int kt = 0; kt < 4; kt++)
#pragma unroll
      for (int r2 = 0; r2 < 4; r2++) {
        const float pv = exp2f(s[kt][r2] - mnew);
        s[kt][r2] = pv;
        rs += pv;
      }
    rs += __shfl_xor(rs, 16);
    rs += __shfl_xor(rs, 32);
    l_st = l_st * alpha + rs;
#pragma unroll
    for (int ht = 0; ht < 4; ht++) o[ht] *= alpha;

#pragma unroll
    for (int kt = 0; kt < 4; kt++) {
      bf16x4 pk;
#pragma unroll
      for (int r2 = 0; r2 < 4; r2++) pk[r2] = (bf16)s[kt][r2];
      *(bf16x4*)&Ps[w][fr][kt * 16 + quad * 4] = pk;
    }

#pragma unroll
    for (int kq = 0; kq < 2; kq++) {
      const bf16x8 bp = *(const bf16x8*)&Ps[w][fr][kq * 32 + fk];
#pragma unroll
      for (int ht = 0; ht < 4; ht++) {
        const bf16x8 av = *(const bf16x8*)&Vt[ht * 16 + fr][kq * 32 + fk];
        o[ht] = mfma_bf16(av, bp, o[ht]);
      }
    }
  }

  const int qq = w * 16 + fr;
  const long pg = (long)gid * 4096 + qq * 64;
#pragma unroll
  for (int ht = 0; ht < 4; ht++)
    *(floatx4*)&po[pg + ht * 16 + quad * 4] = o[ht];
  if (quad == 0) { pm[gid * 64 + qq] = m_st; pl[gid * 64 + qq] = l_st; }
}

// ---------------------------------------------------------------------------
// Combine flash split-K partials: block = (bh, qt), 768 blocks.
// ---------------------------------------------------------------------------
__global__ __launch_bounds__(256)
void flash_comb(const float* __restrict__ po, const float* __restrict__ pm,
                const float* __restrict__ pl, bf16* __restrict__ y) {
  const int bh = blockIdx.x >> 5;
  const int qt = blockIdx.x & 31;
  const int b = bh / H_, h = bh % H_;
  const int nc = (qt >> 3) + 1;
  int bse;
  if      (qt <  8) bse = qt;
  else if (qt < 16) bse = 8  + 2 * (qt - 8);
  else if (qt < 24) bse = 24 + 3 * (qt - 16);
  else              bse = 48 + 4 * (qt - 24);

  const int t = threadIdx.x;
  const int qq = t >> 2, hg = (t & 3) * 16;

  float M = -1e30f;
  for (int c2 = 0; c2 < nc; c2++) M = fmaxf(M, pm[((bse + c2) * 24 + bh) * 64 + qq]);
  float l = 0.f;
  floatx4 o[4] = {};
  for (int c2 = 0; c2 < nc; c2++) {
    const int g = (bse + c2) * 24 + bh;
    const float wgt = exp2f(pm[g * 64 + qq] - M);
    l += wgt * pl[g * 64 + qq];
    const long pg = (long)g * 4096 + qq * 64 + hg;
#pragma unroll
    for (int j = 0; j < 4; j++) {
      const floatx4 t4 = *(const floatx4*)&po[pg + j * 4];
#pragma unroll
      for (int e = 0; e < 4; e++) o[j][e] += wgt * t4[e];
    }
  }
  const float inv = 1.f / l;
  bf16x8 r0, r1;
#pragma unroll
  for (int e = 0; e < 4; e++) {
    r0[e]     = (bf16)(o[0][e] * inv);
    r0[4 + e] = (bf16)(o[1][e] * inv);
    r1[e]     = (bf16)(o[2][e] * inv);
    r1[4 + e] = (bf16)(o[3][e] * inv);
  }
  const long yoff = ((long)b * T_ + qt * 64 + qq) * D_ + h * HD_ + hg;
  *(bf16x8*)&y[yoff]     = r0;
  *(bf16x8*)&y[yoff + 8] = r1;
}

// ---------------------------------------------------------------------------
extern "C" void kernel_launch(void* const* d_in, const int* in_sizes, int n_in,
                              void* d_out, int out_size, void* d_ws, size_t ws_size,
                              hipStream_t stream) {
  const float* x    = (const float*)d_in[0];
  const float* wq   = (const float*)d_in[1];
  const float* wk   = (const float*)d_in[2];
  const float* wv   = (const float*)d_in[3];
  const float* wo   = (const float*)d_in[4];
  const float* w1   = (const float*)d_in[5];
  const float* w2   = (const float*)d_in[6];
  const float* w3   = (const float*)d_in[7];
  const float* anw  = (const float*)d_in[8];
  const float* fnw  = (const float*)d_in[9];
  const float* cosb = (const float*)d_in[10];
  const float* sinb = (const float*)d_in[11];

  char* ws = (char*)d_ws;
  // Layout (bytes), total 88,080,384. Aliasing by lifetime:
  //   po/pm/pl (flash->comb) overlay xm+g region (written later).
  //   w3 partials: pA over wq..w2 bf16 region (dead after w12; w3b at byte
  //   14,155,776 is untouched), pB over qb+kb, pC over yb+hn.
  bf16*  wb  = (bf16*)(ws + 0);                // 18,874,368
  bf16*  wqb = wb;
  bf16*  wkb = wb +  589824;
  bf16*  wvb = wb + 1179648;
  bf16*  wob = wb + 1769472;
  bf16*  w1b = wb + 2359296;
  bf16*  w2b = wb + 4718592;
  bf16*  w3b = wb + 7077888;                   // byte offset 14,155,776
  bf16*  qb  = (bf16*)(ws + 18874368);
  bf16*  kb  = (bf16*)(ws + 25165824);
  bf16*  vt  = (bf16*)(ws + 31457280);
  bf16*  yb  = (bf16*)(ws + 37748736);
  bf16*  hn  = (bf16*)(ws + 44040192);
  float* xm  = (float*)(ws + 50331648);        // 12,582,912
  bf16*  g   = (bf16*)(ws + 62914560);         // 25,165,824
  float* po  = (float*)(ws + 50331648);        // 31,457,280 (pre-xm/g lifetime)
  float* pm  = (float*)(ws + 81788928);
  float* pl  = (float*)(ws + 82280448);
  float* pA  = (float*)(ws + 0);               // 12,582,912 (< w3b offset)
  float* pB  = (float*)(ws + 18874368);        // over qb+kb
  float* pC  = (float*)(ws + 37748736);        // over yb+hn

  prep_k<<<8704, 256, 0, stream>>>(wq, wk, wv, wo, w1, w2, w3, wb, x, anw, hn);
  gemm_qkv<<<dim3(18, 32), 256, 0, stream>>>(hn, wqb, wkb, wvb, qb, kb, vt, cosb, sinb);
  flash_attn<<<1920, 256, 0, stream>>>(qb, kb, vt, po, pm, pl);
  flash_comb<<<768, 256, 0, stream>>>(po, pm, pl, yb);
  gemm_n64<<<384, 256, 0, stream>>>(yb, wob, xm, x, 768, 768);
  rmsnorm_k<<<4096, 256, 0, stream>>>(xm, fnw, hn);
  gemm_w12<<<768, 256, 0, stream>>>(hn, w1b, w2b, g);
  gemm_w3sk<<<1152, 256, 0, stream>>>(g, w3b, pA, pB, pC);
  comb3_k<<<1536, 256, 0, stream>>>(pA, pB, pC, xm, (float*)d_out);
}

// Round 12
// 297.849 us; speedup vs baseline: 1.1961x; 1.1961x over previous
//
#include <hip/hip_runtime.h>
#include <hip/hip_bf16.h>
#include <math.h>

typedef __bf16 bf16;
typedef __bf16 bf16x4 __attribute__((ext_vector_type(4)));
typedef __bf16 bf16x8 __attribute__((ext_vector_type(8)));
typedef float floatx4 __attribute__((ext_vector_type(4)));

#define T_ 2048
#define D_ 768
#define H_ 12
#define HD_ 64
#define FF_ 3072
#define LOG2E 1.44269504f
#define LDP 72   // padded LDS row stride (elems)

__device__ __forceinline__ floatx4 mfma_bf16(bf16x8 a, bf16x8 b, floatx4 c) {
  return __builtin_amdgcn_mfma_f32_16x16x32_bf16(a, b, c, 0, 0, 0);
}

// ---------------------------------------------------------------------------
// Fused prologue: blocks [0,4608) convert 7 fp32 weight mats -> bf16;
// blocks [4608,8704) do attn rmsnorm (row = blk-4608).
// ---------------------------------------------------------------------------
__device__ __forceinline__ void rms_row(const float* __restrict__ x,
                                        const float* __restrict__ wt,
                                        bf16* __restrict__ o, int row, int tid) {
  const long off = (long)row * D_;
  float vals[3];
  float ss = 0.f;
#pragma unroll
  for (int i = 0; i < 3; i++) {
    vals[i] = x[off + tid + i * 256];
    ss += vals[i] * vals[i];
  }
#pragma unroll
  for (int d = 1; d < 64; d <<= 1) ss += __shfl_xor(ss, d);
  __shared__ float wsum[4];
  if ((tid & 63) == 0) wsum[tid >> 6] = ss;
  __syncthreads();
  const float tot = wsum[0] + wsum[1] + wsum[2] + wsum[3];
  const float inv = 1.0f / (sqrtf(tot * (1.0f / 768.0f)) + 1e-6f);
#pragma unroll
  for (int i = 0; i < 3; i++)
    o[off + tid + i * 256] = (bf16)(vals[i] * inv * wt[tid + i * 256]);
}

__global__ __launch_bounds__(256)
void prep_k(const float* __restrict__ wq, const float* __restrict__ wk,
            const float* __restrict__ wv, const float* __restrict__ wo,
            const float* __restrict__ w1, const float* __restrict__ w2,
            const float* __restrict__ w3, bf16* __restrict__ o,
            const float* __restrict__ x, const float* __restrict__ anw,
            bf16* __restrict__ hn) {
  if (blockIdx.x >= 4608) {
    rms_row(x, anw, hn, blockIdx.x - 4608, threadIdx.x);
    return;
  }
  const long i = ((long)blockIdx.x * 256 + threadIdx.x) * 8;
  const float* s;
  if      (i <  589824) s = wq + i;
  else if (i < 1179648) s = wk + (i -  589824);
  else if (i < 1769472) s = wv + (i - 1179648);
  else if (i < 2359296) s = wo + (i - 1769472);
  else if (i < 4718592) s = w1 + (i - 2359296);
  else if (i < 7077888) s = w2 + (i - 4718592);
  else                  s = w3 + (i - 7077888);
  const floatx4 a = *(const floatx4*)s;
  const floatx4 b = *(const floatx4*)(s + 4);
  bf16x8 r;
#pragma unroll
  for (int j = 0; j < 4; j++) { r[j] = (bf16)a[j]; r[4 + j] = (bf16)b[j]; }
  *(bf16x8*)&o[i] = r;
}

// ---------------------------------------------------------------------------
// RMSNorm standalone (ffn norm).
// ---------------------------------------------------------------------------
__global__ __launch_bounds__(256)
void rmsnorm_k(const float* __restrict__ x, const float* __restrict__ wt,
               bf16* __restrict__ o) {
  rms_row(x, wt, o, blockIdx.x, threadIdx.x);
}

// ---------------------------------------------------------------------------
// Fused QKV GEMM, 128x128 tile, BK=64, register-prefetch. Epilogue:
//   widx 0/1 (q,k): RoPE in-register (shfl_xor pair exchange).
//   widx 2   (v)  : store transposed to vt[bh][hd][t] (bf16x4).
// ---------------------------------------------------------------------------
__global__ __launch_bounds__(256)
void gemm_qkv(const bf16* __restrict__ A, const bf16* __restrict__ wq,
              const bf16* __restrict__ wk, const bf16* __restrict__ wv,
              bf16* __restrict__ q, bf16* __restrict__ k, bf16* __restrict__ vt,
              const float* __restrict__ cosb, const float* __restrict__ sinb) {
  const int widx = blockIdx.x / 6;
  const int nb   = blockIdx.x % 6;
  const bf16* W = (widx == 0) ? wq : (widx == 1) ? wk : wv;
  const int m0 = blockIdx.y * 128, n0 = nb * 128;
  const int K = D_;

  __shared__ __align__(16) bf16 As[128 * LDP];
  __shared__ __align__(16) bf16 Ws[128 * LDP];

  const int tid = threadIdx.x;
  const int lane = tid & 63;
  const int wm = tid >> 7;
  const int wn = (tid >> 6) & 1;
  const int fr = lane & 15;
  const int fk = (lane >> 4) * 8;

  floatx4 acc[4][4] = {};

  const int ar = tid >> 3;
  const int ac = (tid & 7) * 8;
  const bf16* Aptr = A + (long)(m0 + ar) * K + ac;
  const bf16* Wptr = W + (long)(n0 + ar) * K + ac;
  const long rstep = (long)32 * K;

  bf16x8 apf[4], wpf[4];
#pragma unroll
  for (int c = 0; c < 4; c++) apf[c] = *(const bf16x8*)(Aptr + c * rstep);
#pragma unroll
  for (int c = 0; c < 4; c++) wpf[c] = *(const bf16x8*)(Wptr + c * rstep);

  const int ns = K >> 6;   // 12
  for (int ks = 0; ks < ns; ks++) {
    __syncthreads();
#pragma unroll
    for (int c = 0; c < 4; c++) *(bf16x8*)&As[(ar + c * 32) * LDP + ac] = apf[c];
#pragma unroll
    for (int c = 0; c < 4; c++) *(bf16x8*)&Ws[(ar + c * 32) * LDP + ac] = wpf[c];
    __syncthreads();
    const long koff = (long)((ks + 1 < ns) ? ks + 1 : ks) * 64;
#pragma unroll
    for (int c = 0; c < 4; c++) apf[c] = *(const bf16x8*)(Aptr + koff + c * rstep);
#pragma unroll
    for (int c = 0; c < 4; c++) wpf[c] = *(const bf16x8*)(Wptr + koff + c * rstep);
#pragma unroll
    for (int kc = 0; kc < 2; kc++) {
      bf16x8 af[4], bfv[4];
#pragma unroll
      for (int i = 0; i < 4; i++) af[i]  = *(const bf16x8*)&As[(wm * 64 + i * 16 + fr) * LDP + kc * 32 + fk];
#pragma unroll
      for (int j = 0; j < 4; j++) bfv[j] = *(const bf16x8*)&Ws[(wn * 64 + j * 16 + fr) * LDP + kc * 32 + fk];
#pragma unroll
      for (int i = 0; i < 4; i++)
#pragma unroll
        for (int j = 0; j < 4; j++)
          acc[i][j] = mfma_bf16(af[i], bfv[j], acc[i][j]);
    }
  }

  const int rb = (lane >> 4) * 4;
  if (widx < 2) {
    bf16* O = (widx == 0) ? q : k;
    const float sgn = (fr & 1) ? 1.f : -1.f;
#pragma unroll
    for (int i = 0; i < 4; i++)
#pragma unroll
      for (int j = 0; j < 4; j++) {
        const int n = n0 + wn * 64 + j * 16 + fr;
        const int d = n & 63;
#pragma unroll
        for (int r = 0; r < 4; r++) {
          const int m = m0 + wm * 64 + i * 16 + rb + r;
          const int pos = m & (T_ - 1);
          const float val = acc[i][j][r];
          const float par = __shfl_xor(val, 1);
          const float cc = cosb[pos * HD_ + d];
          const float ss = sinb[pos * HD_ + d];
          O[(long)m * D_ + n] = (bf16)(val * cc + sgn * par * ss);
        }
      }
  } else {
#pragma unroll
    for (int i = 0; i < 4; i++)
#pragma unroll
      for (int j = 0; j < 4; j++) {
        const int n = n0 + wn * 64 + j * 16 + fr;
        const int m = m0 + wm * 64 + i * 16 + rb;
        const int b = m >> 11;
        const int t = m & (T_ - 1);
        const long row = (long)(b * H_ + (n >> 6)) * HD_ + (n & 63);
        bf16x4 pk;
#pragma unroll
        for (int r = 0; r < 4; r++) pk[r] = (bf16)acc[i][j][r];
        *(bf16x4*)&vt[row * T_ + t] = pk;
      }
  }
}

// ---------------------------------------------------------------------------
// GEMM 128x64 tile for wo (N=768, K=768). 384 blocks, XCD-swizzled.
// Epilogue: f32 C = acc + f32 resid.
// ---------------------------------------------------------------------------
__global__ __launch_bounds__(256)
void gemm_n64(const bf16* __restrict__ A, const bf16* __restrict__ W,
              float* __restrict__ C, const float* __restrict__ resid,
              int N, int K) {
  __shared__ __align__(16) bf16 As[128 * LDP];
  __shared__ __align__(16) bf16 Ws[64 * LDP];

  const int L  = blockIdx.x;
  const int j  = L >> 3;
  const int mb = (L & 7) * 4 + (j / 12);
  const int nb = j % 12;
  const int m0 = mb * 128, n0 = nb * 64;

  const int tid = threadIdx.x;
  const int lane = tid & 63;
  const int wm = tid >> 7;
  const int wn = (tid >> 6) & 1;
  const int fr = lane & 15;
  const int fk = (lane >> 4) * 8;

  floatx4 acc[4][2] = {};

  const int ar = tid >> 3;
  const int ac = (tid & 7) * 8;
  const bf16* Aptr = A + (long)(m0 + ar) * K + ac;
  const bf16* Wptr = W + (long)(n0 + ar) * K + ac;
  const long rstep = (long)32 * K;

  bf16x8 apf[4], wpf[2];
#pragma unroll
  for (int c = 0; c < 4; c++) apf[c] = *(const bf16x8*)(Aptr + c * rstep);
#pragma unroll
  for (int c = 0; c < 2; c++) wpf[c] = *(const bf16x8*)(Wptr + c * rstep);

  const int ns = K >> 6;
  for (int ks = 0; ks < ns; ks++) {
    __syncthreads();
#pragma unroll
    for (int c = 0; c < 4; c++) *(bf16x8*)&As[(ar + c * 32) * LDP + ac] = apf[c];
#pragma unroll
    for (int c = 0; c < 2; c++) *(bf16x8*)&Ws[(ar + c * 32) * LDP + ac] = wpf[c];
    __syncthreads();
    const long koff = (long)((ks + 1 < ns) ? ks + 1 : ks) * 64;
#pragma unroll
    for (int c = 0; c < 4; c++) apf[c] = *(const bf16x8*)(Aptr + koff + c * rstep);
#pragma unroll
    for (int c = 0; c < 2; c++) wpf[c] = *(const bf16x8*)(Wptr + koff + c * rstep);
#pragma unroll
    for (int kc = 0; kc < 2; kc++) {
      bf16x8 af[4], bfv[2];
#pragma unroll
      for (int i = 0; i < 4; i++) af[i]  = *(const bf16x8*)&As[(wm * 64 + i * 16 + fr) * LDP + kc * 32 + fk];
#pragma unroll
      for (int j2 = 0; j2 < 2; j2++) bfv[j2] = *(const bf16x8*)&Ws[(wn * 32 + j2 * 16 + fr) * LDP + kc * 32 + fk];
#pragma unroll
      for (int i = 0; i < 4; i++)
#pragma unroll
        for (int j2 = 0; j2 < 2; j2++)
          acc[i][j2] = mfma_bf16(af[i], bfv[j2], acc[i][j2]);
    }
  }

  const int rb = (lane >> 4) * 4;
#pragma unroll
  for (int i = 0; i < 4; i++)
#pragma unroll
    for (int j2 = 0; j2 < 2; j2++) {
      const int n = n0 + wn * 32 + j2 * 16 + fr;
#pragma unroll
      for (int r = 0; r < 4; r++) {
        const int m = m0 + wm * 64 + i * 16 + rb + r;
        const long idx = (long)m * N + n;
        C[idx] = acc[i][j2][r] + resid[idx];
      }
    }
}

// ---------------------------------------------------------------------------
// w3 GEMM, split-K x3: 1152 blocks, each K-third of 3072 (kbase = s*1024,
// 16 steps of 64). s -> p0/p1/p2 (fp32 partials). XCD-swizzled.
// ---------------------------------------------------------------------------
__global__ __launch_bounds__(256)
void gemm_w3sk(const bf16* __restrict__ A, const bf16* __restrict__ W,
               float* __restrict__ p0, float* __restrict__ p1,
               float* __restrict__ p2) {
  __shared__ __align__(16) bf16 As[128 * LDP];
  __shared__ __align__(16) bf16 Ws[64 * LDP];

  const int L  = blockIdx.x;
  const int j  = L >> 3;                  // 0..143
  const int mb = (L & 7) * 4 + (j / 36);
  const int inner = j % 36;
  const int s  = inner / 12;
  const int nb = inner % 12;
  const int m0 = mb * 128, n0 = nb * 64;
  const int K = FF_;
  const int kbase = s * 1024;
  float* C = (s == 0) ? p0 : (s == 1) ? p1 : p2;

  const int tid = threadIdx.x;
  const int lane = tid & 63;
  const int wm = tid >> 7;
  const int wn = (tid >> 6) & 1;
  const int fr = lane & 15;
  const int fk = (lane >> 4) * 8;

  floatx4 acc[4][2] = {};

  const int ar = tid >> 3;
  const int ac = (tid & 7) * 8;
  const bf16* Aptr = A + (long)(m0 + ar) * K + kbase + ac;
  const bf16* Wptr = W + (long)(n0 + ar) * K + kbase + ac;
  const long rstep = (long)32 * K;

  bf16x8 apf[4], wpf[2];
#pragma unroll
  for (int c = 0; c < 4; c++) apf[c] = *(const bf16x8*)(Aptr + c * rstep);
#pragma unroll
  for (int c = 0; c < 2; c++) wpf[c] = *(const bf16x8*)(Wptr + c * rstep);

  const int ns = 16;
  for (int ks = 0; ks < ns; ks++) {
    __syncthreads();
#pragma unroll
    for (int c = 0; c < 4; c++) *(bf16x8*)&As[(ar + c * 32) * LDP + ac] = apf[c];
#pragma unroll
    for (int c = 0; c < 2; c++) *(bf16x8*)&Ws[(ar + c * 32) * LDP + ac] = wpf[c];
    __syncthreads();
    const long koff = (long)((ks + 1 < ns) ? ks + 1 : ks) * 64;
#pragma unroll
    for (int c = 0; c < 4; c++) apf[c] = *(const bf16x8*)(Aptr + koff + c * rstep);
#pragma unroll
    for (int c = 0; c < 2; c++) wpf[c] = *(const bf16x8*)(Wptr + koff + c * rstep);
#pragma unroll
    for (int kc = 0; kc < 2; kc++) {
      bf16x8 af[4], bfv[2];
#pragma unroll
      for (int i = 0; i < 4; i++) af[i]  = *(const bf16x8*)&As[(wm * 64 + i * 16 + fr) * LDP + kc * 32 + fk];
#pragma unroll
      for (int j2 = 0; j2 < 2; j2++) bfv[j2] = *(const bf16x8*)&Ws[(wn * 32 + j2 * 16 + fr) * LDP + kc * 32 + fk];
#pragma unroll
      for (int i = 0; i < 4; i++)
#pragma unroll
        for (int j2 = 0; j2 < 2; j2++)
          acc[i][j2] = mfma_bf16(af[i], bfv[j2], acc[i][j2]);
    }
  }

  const int rb = (lane >> 4) * 4;
#pragma unroll
  for (int i = 0; i < 4; i++)
#pragma unroll
    for (int j2 = 0; j2 < 2; j2++) {
      const int n = n0 + wn * 32 + j2 * 16 + fr;
#pragma unroll
      for (int r = 0; r < 4; r++) {
        const int m = m0 + wm * 64 + i * 16 + rb + r;
        C[(long)m * D_ + n] = acc[i][j2][r];
      }
    }
}

// out = p0 + p1 + p2 + xm (fp32), 3.1M elems, 8/thread.
__global__ __launch_bounds__(256)
void comb3_k(const float* __restrict__ p0, const float* __restrict__ p1,
             const float* __restrict__ p2, const float* __restrict__ xm,
             float* __restrict__ out) {
  const long i = ((long)blockIdx.x * 256 + threadIdx.x) * 8;
#pragma unroll
  for (int c = 0; c < 2; c++) {
    const floatx4 a = *(const floatx4*)&p0[i + c * 4];
    const floatx4 b = *(const floatx4*)&p1[i + c * 4];
    const floatx4 e = *(const floatx4*)&p2[i + c * 4];
    const floatx4 d = *(const floatx4*)&xm[i + c * 4];
    floatx4 r;
#pragma unroll
    for (int q = 0; q < 4; q++) r[q] = a[q] + b[q] + e[q] + d[q];
    *(floatx4*)&out[i + c * 4] = r;
  }
}

// ---------------------------------------------------------------------------
// Fused w1/w2 GEMM + silu-mul. 128x128 DUAL tile, all operands LDS-staged
// with register prefetch (REVERT of the direct-global-B experiment: staging
// is the latency-hiding mechanism, not just BW amortization). 768 blocks
// (32 mb x 24 nb), 3 n-stripes/XCD, mb outer. LDS 55.3 KB -> 2 blocks/CU.
// ---------------------------------------------------------------------------
__global__ __launch_bounds__(256, 2)
void gemm_w12(const bf16* __restrict__ A, const bf16* __restrict__ W1,
              const bf16* __restrict__ W2, bf16* __restrict__ G) {
  __shared__ __align__(16) bf16 As[128 * LDP];
  __shared__ __align__(16) bf16 W1s[128 * LDP];
  __shared__ __align__(16) bf16 W2s[128 * LDP];

  const int L  = blockIdx.x;
  const int j  = L >> 3;                  // 0..95
  const int mb = j / 3;                   // 0..31 (outer per XCD)
  const int nb = (L & 7) * 3 + (j % 3);   // 0..23
  const int m0 = mb * 128, n0 = nb * 128;
  const int K = D_;

  const int tid = threadIdx.x;
  const int lane = tid & 63;
  const int wm = tid >> 7;
  const int wn = (tid >> 6) & 1;
  const int fr = lane & 15;
  const int fk = (lane >> 4) * 8;

  floatx4 acc1[4][4] = {}, acc2[4][4] = {};

  const int ar = tid >> 3;
  const int ac = (tid & 7) * 8;
  const bf16* Aptr  = A  + (long)(m0 + ar) * K + ac;
  const bf16* W1ptr = W1 + (long)(n0 + ar) * K + ac;
  const bf16* W2ptr = W2 + (long)(n0 + ar) * K + ac;
  const long rstep = (long)32 * K;

  bf16x8 apf[4], w1pf[4], w2pf[4];
#pragma unroll
  for (int c = 0; c < 4; c++) { apf[c]  = *(const bf16x8*)(Aptr  + c * rstep);
                                w1pf[c] = *(const bf16x8*)(W1ptr + c * rstep);
                                w2pf[c] = *(const bf16x8*)(W2ptr + c * rstep); }

  const int ns = K >> 6;   // 12
  for (int ks = 0; ks < ns; ks++) {
    __syncthreads();
#pragma unroll
    for (int c = 0; c < 4; c++) { *(bf16x8*)&As[(ar + c * 32) * LDP + ac]  = apf[c];
                                  *(bf16x8*)&W1s[(ar + c * 32) * LDP + ac] = w1pf[c];
                                  *(bf16x8*)&W2s[(ar + c * 32) * LDP + ac] = w2pf[c]; }
    __syncthreads();
    const long koff = (long)((ks + 1 < ns) ? ks + 1 : ks) * 64;
#pragma unroll
    for (int c = 0; c < 4; c++) { apf[c]  = *(const bf16x8*)(Aptr  + koff + c * rstep);
                                  w1pf[c] = *(const bf16x8*)(W1ptr + koff + c * rstep);
                                  w2pf[c] = *(const bf16x8*)(W2ptr + koff + c * rstep); }
#pragma unroll
    for (int kc = 0; kc < 2; kc++) {
      bf16x8 af[4];
#pragma unroll
      for (int i = 0; i < 4; i++) af[i] = *(const bf16x8*)&As[(wm * 64 + i * 16 + fr) * LDP + kc * 32 + fk];
      {
        bf16x8 b1[4];
#pragma unroll
        for (int jj = 0; jj < 4; jj++) b1[jj] = *(const bf16x8*)&W1s[(wn * 64 + jj * 16 + fr) * LDP + kc * 32 + fk];
#pragma unroll
        for (int i = 0; i < 4; i++)
#pragma unroll
          for (int jj = 0; jj < 4; jj++)
            acc1[i][jj] = mfma_bf16(af[i], b1[jj], acc1[i][jj]);
      }
      {
        bf16x8 b2[4];
#pragma unroll
        for (int jj = 0; jj < 4; jj++) b2[jj] = *(const bf16x8*)&W2s[(wn * 64 + jj * 16 + fr) * LDP + kc * 32 + fk];
#pragma unroll
        for (int i = 0; i < 4; i++)
#pragma unroll
          for (int jj = 0; jj < 4; jj++)
            acc2[i][jj] = mfma_bf16(af[i], b2[jj], acc2[i][jj]);
      }
    }
  }

  const int rb = (lane >> 4) * 4;
#pragma unroll
  for (int i = 0; i < 4; i++)
#pragma unroll
    for (int jj = 0; jj < 4; jj++) {
      const int n = n0 + wn * 64 + jj * 16 + fr;
#pragma unroll
      for (int r = 0; r < 4; r++) {
        const int m = m0 + wm * 64 + i * 16 + rb + r;
        const float a1 = acc1[i][jj][r];
        const float a2 = acc2[i][jj][r];
        const float s = a1 / (1.f + exp2f(-a1 * LOG2E));
        G[(long)m * FF_ + n] = (bf16)(s * a2);
      }
    }
}

// ---------------------------------------------------------------------------
// Flash attention, split-K over KV. blockIdx = r*24 + bh (XCD-local K/V).
// Register-prefetch of next round's K/V overlaps global latency with compute.
// ---------------------------------------------------------------------------
__global__ __launch_bounds__(256, 4)
void flash_attn(const bf16* __restrict__ q, const bf16* __restrict__ k,
                const bf16* __restrict__ vtg, float* __restrict__ po,
                float* __restrict__ pm, float* __restrict__ pl) {
  const int gid = blockIdx.x;
  const int bh = gid % 24;
  const int r  = gid / 24;
  int qt, c;
  if (r < 8)       { qt = r; c = 0; }
  else if (r < 24) { qt = 8 + ((r - 8) >> 1); c = (r - 8) & 1; }
  else if (r < 48) { const int u = r - 24; const int d = u / 3; qt = 16 + d; c = u - d * 3; }
  else             { const int u = r - 48; qt = 24 + (u >> 2); c = u & 3; }
  const int b  = bh / H_;
  const int h  = bh % H_;
  const int q0 = qt * 64;
  const int tbeg = c * 8;
  const int tend = (tbeg + 7 < qt) ? tbeg + 7 : qt;

  __shared__ __align__(16) bf16 Qs[64][72];
  __shared__ __align__(16) bf16 Ks[64][72];
  __shared__ __align__(16) bf16 Vt[64][72];
  __shared__ __align__(16) bf16 Ps[4][16][72];

  const int tid = threadIdx.x, lane = tid & 63, w = tid >> 6;
  const int fr = lane & 15, quad = lane >> 4, fk = quad * 8;
  const long base = ((long)b * T_) * D_ + h * HD_;
  const long vbase = (long)bh * HD_ * T_;

  const int srow = tid >> 2, scol = (tid & 3) * 16;
  {
    const long g = base + (long)(q0 + srow) * D_ + scol;
    *(bf16x8*)&Qs[srow][scol]     = *(const bf16x8*)&q[g];
    *(bf16x8*)&Qs[srow][scol + 8] = *(const bf16x8*)&q[g + 8];
  }

  const bf16* kgp = k + base + (long)srow * D_ + scol;
  const bf16* vgp = vtg + vbase + (long)srow * T_ + scol;
  bf16x8 kpf0 = *(const bf16x8*)(kgp + (long)tbeg * 64 * D_);
  bf16x8 kpf1 = *(const bf16x8*)(kgp + (long)tbeg * 64 * D_ + 8);
  bf16x8 vpf0 = *(const bf16x8*)(vgp + tbeg * 64);
  bf16x8 vpf1 = *(const bf16x8*)(vgp + tbeg * 64 + 8);

  float m_st = -1e30f, l_st = 0.f;
  floatx4 o[4] = {};
  const float SC = 0.125f * LOG2E;

  for (int t = tbeg; t <= tend; t++) {
    __syncthreads();
    *(bf16x8*)&Ks[srow][scol]     = kpf0;
    *(bf16x8*)&Ks[srow][scol + 8] = kpf1;
    *(bf16x8*)&Vt[srow][scol]     = vpf0;
    *(bf16x8*)&Vt[srow][scol + 8] = vpf1;
    __syncthreads();
    const int tn = (t + 1 <= tend) ? t + 1 : t;
    kpf0 = *(const bf16x8*)(kgp + (long)tn * 64 * D_);
    kpf1 = *(const bf16x8*)(kgp + (long)tn * 64 * D_ + 8);
    vpf0 = *(const bf16x8*)(vgp + tn * 64);
    vpf1 = *(const bf16x8*)(vgp + tn * 64 + 8);

    floatx4 s[4] = {};
#pragma unroll
    for (int kd = 0; kd < 2; kd++) {
      const bf16x8 bq = *(const bf16x8*)&Qs[w * 16 + fr][kd * 32 + fk];
#pragma unroll
      for (int kt = 0; kt < 4; kt++) {
        const bf16x8 ak = *(const bf16x8*)&Ks[kt * 16 + fr][kd * 32 + fk];
        s[kt] = mfma_bf16(ak, bq, s[kt]);
      }
    }

    if (t == qt) {
      const int qloc = w * 16 + fr;
#pragma unroll
      for (int kt = 0; kt < 4; kt++)
#pragma unroll
        for (int r2 = 0; r2 < 4; r2++) {
          const int kvloc = kt * 16 + quad * 4 + r2;
          s[kt][r2] = (kvloc > qloc) ? -1e30f : s[kt][r2] * SC;
        }
    } else {
#pragma unroll
      for (int kt = 0; kt < 4; kt++)
#pragma unroll
        for (int r2 = 0; r2 < 4; r2++) s[kt][r2] *= SC;
    }

    float mx = -1e30f;
#pragma unroll
    for (int kt = 0; kt < 4; kt++)
#pragma unroll
      for (int r2 = 0; r2 < 4; r2++) mx = fmaxf(mx, s[kt][r2]);
    mx = fmaxf(mx, __shfl_xor(mx, 16));
    mx = fmaxf(mx, __shfl_xor(mx, 32));
    const float mnew  = fmaxf(m_st, mx);
    const float alpha = exp2f(m_st - mnew);
    m_st = mnew;
    float rs = 0.f;
#pragma unroll
    for (int kt = 0; kt < 4; kt++)
#pragma unroll
      for (int r2 = 0; r2 < 4; r2++) {
        const float pv = exp2f(s[kt][r2] - mnew);
        s[kt][r2] = pv;
        rs += pv;
      }
    rs += __shfl_xor(rs, 16);
    rs += __shfl_xor(rs, 32);
    l_st = l_st * alpha + rs;
#pragma unroll
    for (int ht = 0; ht < 4; ht++) o[ht] *= alpha;

#pragma unroll
    for (int kt = 0; kt < 4; kt++) {
      bf16x4 pk;
#pragma unroll
      for (int r2 = 0; r2 < 4; r2++) pk[r2] = (bf16)s[kt][r2];
      *(bf16x4*)&Ps[w][fr][kt * 16 + quad * 4] = pk;
    }

#pragma unroll
    for (int kq = 0; kq < 2; kq++) {
      const bf16x8 bp = *(const bf16x8*)&Ps[w][fr][kq * 32 + fk];
#pragma unroll
      for (int ht = 0; ht < 4; ht++) {
        const bf16x8 av = *(const bf16x8*)&Vt[ht * 16 + fr][kq * 32 + fk];
        o[ht] = mfma_bf16(av, bp, o[ht]);
      }
    }
  }

  const int qq = w * 16 + fr;
  const long pg = (long)gid * 4096 + qq * 64;
#pragma unroll
  for (int ht = 0; ht < 4; ht++)
    *(floatx4*)&po[pg + ht * 16 + quad * 4] = o[ht];
  if (quad == 0) { pm[gid * 64 + qq] = m_st; pl[gid * 64 + qq] = l_st; }
}

// ---------------------------------------------------------------------------
// Combine flash split-K partials: block = (bh, qt), 768 blocks.
// ---------------------------------------------------------------------------
__global__ __launch_bounds__(256)
void flash_comb(const float* __restrict__ po, const float* __restrict__ pm,
                const float* __restrict__ pl, bf16* __restrict__ y) {
  const int bh = blockIdx.x >> 5;
  const int qt = blockIdx.x & 31;
  const int b = bh / H_, h = bh % H_;
  const int nc = (qt >> 3) + 1;
  int bse;
  if      (qt <  8) bse = qt;
  else if (qt < 16) bse = 8  + 2 * (qt - 8);
  else if (qt < 24) bse = 24 + 3 * (qt - 16);
  else              bse = 48 + 4 * (qt - 24);

  const int t = threadIdx.x;
  const int qq = t >> 2, hg = (t & 3) * 16;

  float M = -1e30f;
  for (int c2 = 0; c2 < nc; c2++) M = fmaxf(M, pm[((bse + c2) * 24 + bh) * 64 + qq]);
  float l = 0.f;
  floatx4 o[4] = {};
  for (int c2 = 0; c2 < nc; c2++) {
    const int g = (bse + c2) * 24 + bh;
    const float wgt = exp2f(pm[g * 64 + qq] - M);
    l += wgt * pl[g * 64 + qq];
    const long pg = (long)g * 4096 + qq * 64 + hg;
#pragma unroll
    for (int j = 0; j < 4; j++) {
      const floatx4 t4 = *(const floatx4*)&po[pg + j * 4];
#pragma unroll
      for (int e = 0; e < 4; e++) o[j][e] += wgt * t4[e];
    }
  }
  const float inv = 1.f / l;
  bf16x8 r0, r1;
#pragma unroll
  for (int e = 0; e < 4; e++) {
    r0[e]     = (bf16)(o[0][e] * inv);
    r0[4 + e] = (bf16)(o[1][e] * inv);
    r1[e]     = (bf16)(o[2][e] * inv);
    r1[4 + e] = (bf16)(o[3][e] * inv);
  }
  const long yoff = ((long)b * T_ + qt * 64 + qq) * D_ + h * HD_ + hg;
  *(bf16x8*)&y[yoff]     = r0;
  *(bf16x8*)&y[yoff + 8] = r1;
}

// ---------------------------------------------------------------------------
extern "C" void kernel_launch(void* const* d_in, const int* in_sizes, int n_in,
                              void* d_out, int out_size, void* d_ws, size_t ws_size,
                              hipStream_t stream) {
  const float* x    = (const float*)d_in[0];
  const float* wq   = (const float*)d_in[1];
  const float* wk   = (const float*)d_in[2];
  const float* wv   = (const float*)d_in[3];
  const float* wo   = (const float*)d_in[4];
  const float* w1   = (const float*)d_in[5];
  const float* w2   = (const float*)d_in[6];
  const float* w3   = (const float*)d_in[7];
  const float* anw  = (const float*)d_in[8];
  const float* fnw  = (const float*)d_in[9];
  const float* cosb = (const float*)d_in[10];
  const float* sinb = (const float*)d_in[11];

  char* ws = (char*)d_ws;
  // Layout (bytes), total 88,080,384. Aliasing by lifetime:
  //   po/pm/pl (flash->comb) overlay xm+g region (written later).
  //   w3 partials: pA over wq..w2 bf16 region (dead after w12; w3b at byte
  //   14,155,776 is untouched), pB over qb+kb, pC over yb+hn.
  bf16*  wb  = (bf16*)(ws + 0);                // 18,874,368
  bf16*  wqb = wb;
  bf16*  wkb = wb +  589824;
  bf16*  wvb = wb + 1179648;
  bf16*  wob = wb + 1769472;
  bf16*  w1b = wb + 2359296;
  bf16*  w2b = wb + 4718592;
  bf16*  w3b = wb + 7077888;                   // byte offset 14,155,776
  bf16*  qb  = (bf16*)(ws + 18874368);
  bf16*  kb  = (bf16*)(ws + 25165824);
  bf16*  vt  = (bf16*)(ws + 31457280);
  bf16*  yb  = (bf16*)(ws + 37748736);
  bf16*  hn  = (bf16*)(ws + 44040192);
  float* xm  = (float*)(ws + 50331648);        // 12,582,912
  bf16*  g   = (bf16*)(ws + 62914560);         // 25,165,824
  float* po  = (float*)(ws + 50331648);        // 31,457,280 (pre-xm/g lifetime)
  float* pm  = (float*)(ws + 81788928);
  float* pl  = (float*)(ws + 82280448);
  float* pA  = (float*)(ws + 0);               // 12,582,912 (< w3b offset)
  float* pB  = (float*)(ws + 18874368);        // over qb+kb
  float* pC  = (float*)(ws + 37748736);        // over yb+hn

  prep_k<<<8704, 256, 0, stream>>>(wq, wk, wv, wo, w1, w2, w3, wb, x, anw, hn);
  gemm_qkv<<<dim3(18, 32), 256, 0, stream>>>(hn, wqb, wkb, wvb, qb, kb, vt, cosb, sinb);
  flash_attn<<<1920, 256, 0, stream>>>(qb, kb, vt, po, pm, pl);
  flash_comb<<<768, 256, 0, stream>>>(po, pm, pl, yb);
  gemm_n64<<<384, 256, 0, stream>>>(yb, wob, xm, x, 768, 768);
  rmsnorm_k<<<4096, 256, 0, stream>>>(xm, fnw, hn);
  gemm_w12<<<768, 256, 0, stream>>>(hn, w1b, w2b, g);
  gemm_w3sk<<<1152, 256, 0, stream>>>(g, w3b, pA, pB, pC);
  comb3_k<<<1536, 256, 0, stream>>>(pA, pB, pC, xm, (float*)d_out);
}

// Round 13
// 294.078 us; speedup vs baseline: 1.2114x; 1.0128x over previous
//
#include <hip/hip_runtime.h>
#include <hip/hip_bf16.h>
#include <math.h>

typedef __bf16 bf16;
typedef __bf16 bf16x4 __attribute__((ext_vector_type(4)));
typedef __bf16 bf16x8 __attribute__((ext_vector_type(8)));
typedef float floatx4 __attribute__((ext_vector_type(4)));

#define T_ 2048
#define D_ 768
#define H_ 12
#define HD_ 64
#define FF_ 3072
#define LOG2E 1.44269504f
#define LDP 72   // padded LDS row stride (elems)

__device__ __forceinline__ floatx4 mfma_bf16(bf16x8 a, bf16x8 b, floatx4 c) {
  return __builtin_amdgcn_mfma_f32_16x16x32_bf16(a, b, c, 0, 0, 0);
}

// ---------------------------------------------------------------------------
// Fused prologue: blocks [0,4608) convert 7 fp32 weight mats -> bf16;
// blocks [4608,8704) do attn rmsnorm (row = blk-4608).
// ---------------------------------------------------------------------------
__device__ __forceinline__ void rms_row(const float* __restrict__ x,
                                        const float* __restrict__ wt,
                                        bf16* __restrict__ o, int row, int tid) {
  const long off = (long)row * D_;
  float vals[3];
  float ss = 0.f;
#pragma unroll
  for (int i = 0; i < 3; i++) {
    vals[i] = x[off + tid + i * 256];
    ss += vals[i] * vals[i];
  }
#pragma unroll
  for (int d = 1; d < 64; d <<= 1) ss += __shfl_xor(ss, d);
  __shared__ float wsum[4];
  if ((tid & 63) == 0) wsum[tid >> 6] = ss;
  __syncthreads();
  const float tot = wsum[0] + wsum[1] + wsum[2] + wsum[3];
  const float inv = 1.0f / (sqrtf(tot * (1.0f / 768.0f)) + 1e-6f);
#pragma unroll
  for (int i = 0; i < 3; i++)
    o[off + tid + i * 256] = (bf16)(vals[i] * inv * wt[tid + i * 256]);
}

__global__ __launch_bounds__(256)
void prep_k(const float* __restrict__ wq, const float* __restrict__ wk,
            const float* __restrict__ wv, const float* __restrict__ wo,
            const float* __restrict__ w1, const float* __restrict__ w2,
            const float* __restrict__ w3, bf16* __restrict__ o,
            const float* __restrict__ x, const float* __restrict__ anw,
            bf16* __restrict__ hn) {
  if (blockIdx.x >= 4608) {
    rms_row(x, anw, hn, blockIdx.x - 4608, threadIdx.x);
    return;
  }
  const long i = ((long)blockIdx.x * 256 + threadIdx.x) * 8;
  const float* s;
  if      (i <  589824) s = wq + i;
  else if (i < 1179648) s = wk + (i -  589824);
  else if (i < 1769472) s = wv + (i - 1179648);
  else if (i < 2359296) s = wo + (i - 1769472);
  else if (i < 4718592) s = w1 + (i - 2359296);
  else if (i < 7077888) s = w2 + (i - 4718592);
  else                  s = w3 + (i - 7077888);
  const floatx4 a = *(const floatx4*)s;
  const floatx4 b = *(const floatx4*)(s + 4);
  bf16x8 r;
#pragma unroll
  for (int j = 0; j < 4; j++) { r[j] = (bf16)a[j]; r[4 + j] = (bf16)b[j]; }
  *(bf16x8*)&o[i] = r;
}

// ---------------------------------------------------------------------------
// RMSNorm standalone (ffn norm).
// ---------------------------------------------------------------------------
__global__ __launch_bounds__(256)
void rmsnorm_k(const float* __restrict__ x, const float* __restrict__ wt,
               bf16* __restrict__ o) {
  rms_row(x, wt, o, blockIdx.x, threadIdx.x);
}

// ---------------------------------------------------------------------------
// Fused QKV GEMM, 128x128 tile, BK=64, register-prefetch. Epilogue:
//   widx 0/1 (q,k): RoPE in-register (shfl_xor pair exchange).
//   widx 2   (v)  : store transposed to vt[bh][hd][t] (bf16x4).
// ---------------------------------------------------------------------------
__global__ __launch_bounds__(256)
void gemm_qkv(const bf16* __restrict__ A, const bf16* __restrict__ wq,
              const bf16* __restrict__ wk, const bf16* __restrict__ wv,
              bf16* __restrict__ q, bf16* __restrict__ k, bf16* __restrict__ vt,
              const float* __restrict__ cosb, const float* __restrict__ sinb) {
  const int widx = blockIdx.x / 6;
  const int nb   = blockIdx.x % 6;
  const bf16* W = (widx == 0) ? wq : (widx == 1) ? wk : wv;
  const int m0 = blockIdx.y * 128, n0 = nb * 128;
  const int K = D_;

  __shared__ __align__(16) bf16 As[128 * LDP];
  __shared__ __align__(16) bf16 Ws[128 * LDP];

  const int tid = threadIdx.x;
  const int lane = tid & 63;
  const int wm = tid >> 7;
  const int wn = (tid >> 6) & 1;
  const int fr = lane & 15;
  const int fk = (lane >> 4) * 8;

  floatx4 acc[4][4] = {};

  const int ar = tid >> 3;
  const int ac = (tid & 7) * 8;
  const bf16* Aptr = A + (long)(m0 + ar) * K + ac;
  const bf16* Wptr = W + (long)(n0 + ar) * K + ac;
  const long rstep = (long)32 * K;

  bf16x8 apf[4], wpf[4];
#pragma unroll
  for (int c = 0; c < 4; c++) apf[c] = *(const bf16x8*)(Aptr + c * rstep);
#pragma unroll
  for (int c = 0; c < 4; c++) wpf[c] = *(const bf16x8*)(Wptr + c * rstep);

  const int ns = K >> 6;   // 12
  for (int ks = 0; ks < ns; ks++) {
    __syncthreads();
#pragma unroll
    for (int c = 0; c < 4; c++) *(bf16x8*)&As[(ar + c * 32) * LDP + ac] = apf[c];
#pragma unroll
    for (int c = 0; c < 4; c++) *(bf16x8*)&Ws[(ar + c * 32) * LDP + ac] = wpf[c];
    __syncthreads();
    const long koff = (long)((ks + 1 < ns) ? ks + 1 : ks) * 64;
#pragma unroll
    for (int c = 0; c < 4; c++) apf[c] = *(const bf16x8*)(Aptr + koff + c * rstep);
#pragma unroll
    for (int c = 0; c < 4; c++) wpf[c] = *(const bf16x8*)(Wptr + koff + c * rstep);
#pragma unroll
    for (int kc = 0; kc < 2; kc++) {
      bf16x8 af[4], bfv[4];
#pragma unroll
      for (int i = 0; i < 4; i++) af[i]  = *(const bf16x8*)&As[(wm * 64 + i * 16 + fr) * LDP + kc * 32 + fk];
#pragma unroll
      for (int j = 0; j < 4; j++) bfv[j] = *(const bf16x8*)&Ws[(wn * 64 + j * 16 + fr) * LDP + kc * 32 + fk];
#pragma unroll
      for (int i = 0; i < 4; i++)
#pragma unroll
        for (int j = 0; j < 4; j++)
          acc[i][j] = mfma_bf16(af[i], bfv[j], acc[i][j]);
    }
  }

  const int rb = (lane >> 4) * 4;
  if (widx < 2) {
    bf16* O = (widx == 0) ? q : k;
    const float sgn = (fr & 1) ? 1.f : -1.f;
#pragma unroll
    for (int i = 0; i < 4; i++)
#pragma unroll
      for (int j = 0; j < 4; j++) {
        const int n = n0 + wn * 64 + j * 16 + fr;
        const int d = n & 63;
#pragma unroll
        for (int r = 0; r < 4; r++) {
          const int m = m0 + wm * 64 + i * 16 + rb + r;
          const int pos = m & (T_ - 1);
          const float val = acc[i][j][r];
          const float par = __shfl_xor(val, 1);
          const float cc = cosb[pos * HD_ + d];
          const float ss = sinb[pos * HD_ + d];
          O[(long)m * D_ + n] = (bf16)(val * cc + sgn * par * ss);
        }
      }
  } else {
#pragma unroll
    for (int i = 0; i < 4; i++)
#pragma unroll
      for (int j = 0; j < 4; j++) {
        const int n = n0 + wn * 64 + j * 16 + fr;
        const int m = m0 + wm * 64 + i * 16 + rb;
        const int b = m >> 11;
        const int t = m & (T_ - 1);
        const long row = (long)(b * H_ + (n >> 6)) * HD_ + (n & 63);
        bf16x4 pk;
#pragma unroll
        for (int r = 0; r < 4; r++) pk[r] = (bf16)acc[i][j][r];
        *(bf16x4*)&vt[row * T_ + t] = pk;
      }
  }
}

// ---------------------------------------------------------------------------
// GEMM 128x64 tile for wo (N=768, K=768). 384 blocks, XCD-swizzled.
// Epilogue: f32 C = acc + f32 resid.
// ---------------------------------------------------------------------------
__global__ __launch_bounds__(256)
void gemm_n64(const bf16* __restrict__ A, const bf16* __restrict__ W,
              float* __restrict__ C, const float* __restrict__ resid,
              int N, int K) {
  __shared__ __align__(16) bf16 As[128 * LDP];
  __shared__ __align__(16) bf16 Ws[64 * LDP];

  const int L  = blockIdx.x;
  const int j  = L >> 3;
  const int mb = (L & 7) * 4 + (j / 12);
  const int nb = j % 12;
  const int m0 = mb * 128, n0 = nb * 64;

  const int tid = threadIdx.x;
  const int lane = tid & 63;
  const int wm = tid >> 7;
  const int wn = (tid >> 6) & 1;
  const int fr = lane & 15;
  const int fk = (lane >> 4) * 8;

  floatx4 acc[4][2] = {};

  const int ar = tid >> 3;
  const int ac = (tid & 7) * 8;
  const bf16* Aptr = A + (long)(m0 + ar) * K + ac;
  const bf16* Wptr = W + (long)(n0 + ar) * K + ac;
  const long rstep = (long)32 * K;

  bf16x8 apf[4], wpf[2];
#pragma unroll
  for (int c = 0; c < 4; c++) apf[c] = *(const bf16x8*)(Aptr + c * rstep);
#pragma unroll
  for (int c = 0; c < 2; c++) wpf[c] = *(const bf16x8*)(Wptr + c * rstep);

  const int ns = K >> 6;
  for (int ks = 0; ks < ns; ks++) {
    __syncthreads();
#pragma unroll
    for (int c = 0; c < 4; c++) *(bf16x8*)&As[(ar + c * 32) * LDP + ac] = apf[c];
#pragma unroll
    for (int c = 0; c < 2; c++) *(bf16x8*)&Ws[(ar + c * 32) * LDP + ac] = wpf[c];
    __syncthreads();
    const long koff = (long)((ks + 1 < ns) ? ks + 1 : ks) * 64;
#pragma unroll
    for (int c = 0; c < 4; c++) apf[c] = *(const bf16x8*)(Aptr + koff + c * rstep);
#pragma unroll
    for (int c = 0; c < 2; c++) wpf[c] = *(const bf16x8*)(Wptr + koff + c * rstep);
#pragma unroll
    for (int kc = 0; kc < 2; kc++) {
      bf16x8 af[4], bfv[2];
#pragma unroll
      for (int i = 0; i < 4; i++) af[i]  = *(const bf16x8*)&As[(wm * 64 + i * 16 + fr) * LDP + kc * 32 + fk];
#pragma unroll
      for (int j2 = 0; j2 < 2; j2++) bfv[j2] = *(const bf16x8*)&Ws[(wn * 32 + j2 * 16 + fr) * LDP + kc * 32 + fk];
#pragma unroll
      for (int i = 0; i < 4; i++)
#pragma unroll
        for (int j2 = 0; j2 < 2; j2++)
          acc[i][j2] = mfma_bf16(af[i], bfv[j2], acc[i][j2]);
    }
  }

  const int rb = (lane >> 4) * 4;
#pragma unroll
  for (int i = 0; i < 4; i++)
#pragma unroll
    for (int j2 = 0; j2 < 2; j2++) {
      const int n = n0 + wn * 32 + j2 * 16 + fr;
#pragma unroll
      for (int r = 0; r < 4; r++) {
        const int m = m0 + wm * 64 + i * 16 + rb + r;
        const long idx = (long)m * N + n;
        C[idx] = acc[i][j2][r] + resid[idx];
      }
    }
}

// ---------------------------------------------------------------------------
// w3 GEMM, split-K x2 (measured best at r9): 768 blocks, each K-half of
// 3072 (24 steps). s=0 -> p0, s=1 -> p1 (fp32 partials). XCD-swizzled.
// ---------------------------------------------------------------------------
__global__ __launch_bounds__(256)
void gemm_w3sk(const bf16* __restrict__ A, const bf16* __restrict__ W,
               float* __restrict__ p0, float* __restrict__ p1) {
  __shared__ __align__(16) bf16 As[128 * LDP];
  __shared__ __align__(16) bf16 Ws[64 * LDP];

  const int L  = blockIdx.x;
  const int j  = L >> 3;                  // 0..95
  const int mb = (L & 7) * 4 + (j / 24);
  const int inner = j % 24;
  const int s  = inner / 12;
  const int nb = inner % 12;
  const int m0 = mb * 128, n0 = nb * 64;
  const int K = FF_;
  const int kbase = s * 1536;
  float* C = s ? p1 : p0;

  const int tid = threadIdx.x;
  const int lane = tid & 63;
  const int wm = tid >> 7;
  const int wn = (tid >> 6) & 1;
  const int fr = lane & 15;
  const int fk = (lane >> 4) * 8;

  floatx4 acc[4][2] = {};

  const int ar = tid >> 3;
  const int ac = (tid & 7) * 8;
  const bf16* Aptr = A + (long)(m0 + ar) * K + kbase + ac;
  const bf16* Wptr = W + (long)(n0 + ar) * K + kbase + ac;
  const long rstep = (long)32 * K;

  bf16x8 apf[4], wpf[2];
#pragma unroll
  for (int c = 0; c < 4; c++) apf[c] = *(const bf16x8*)(Aptr + c * rstep);
#pragma unroll
  for (int c = 0; c < 2; c++) wpf[c] = *(const bf16x8*)(Wptr + c * rstep);

  const int ns = 24;
  for (int ks = 0; ks < ns; ks++) {
    __syncthreads();
#pragma unroll
    for (int c = 0; c < 4; c++) *(bf16x8*)&As[(ar + c * 32) * LDP + ac] = apf[c];
#pragma unroll
    for (int c = 0; c < 2; c++) *(bf16x8*)&Ws[(ar + c * 32) * LDP + ac] = wpf[c];
    __syncthreads();
    const long koff = (long)((ks + 1 < ns) ? ks + 1 : ks) * 64;
#pragma unroll
    for (int c = 0; c < 4; c++) apf[c] = *(const bf16x8*)(Aptr + koff + c * rstep);
#pragma unroll
    for (int c = 0; c < 2; c++) wpf[c] = *(const bf16x8*)(Wptr + koff + c * rstep);
#pragma unroll
    for (int kc = 0; kc < 2; kc++) {
      bf16x8 af[4], bfv[2];
#pragma unroll
      for (int i = 0; i < 4; i++) af[i]  = *(const bf16x8*)&As[(wm * 64 + i * 16 + fr) * LDP + kc * 32 + fk];
#pragma unroll
      for (int j2 = 0; j2 < 2; j2++) bfv[j2] = *(const bf16x8*)&Ws[(wn * 32 + j2 * 16 + fr) * LDP + kc * 32 + fk];
#pragma unroll
      for (int i = 0; i < 4; i++)
#pragma unroll
        for (int j2 = 0; j2 < 2; j2++)
          acc[i][j2] = mfma_bf16(af[i], bfv[j2], acc[i][j2]);
    }
  }

  const int rb = (lane >> 4) * 4;
#pragma unroll
  for (int i = 0; i < 4; i++)
#pragma unroll
    for (int j2 = 0; j2 < 2; j2++) {
      const int n = n0 + wn * 32 + j2 * 16 + fr;
#pragma unroll
      for (int r = 0; r < 4; r++) {
        const int m = m0 + wm * 64 + i * 16 + rb + r;
        C[(long)m * D_ + n] = acc[i][j2][r];
      }
    }
}

// out = p0 + p1 + xm (fp32), 3.1M elems, 8/thread.
__global__ __launch_bounds__(256)
void comb3_k(const float* __restrict__ p0, const float* __restrict__ p1,
             const float* __restrict__ xm, float* __restrict__ out) {
  const long i = ((long)blockIdx.x * 256 + threadIdx.x) * 8;
#pragma unroll
  for (int c = 0; c < 2; c++) {
    const floatx4 a = *(const floatx4*)&p0[i + c * 4];
    const floatx4 b = *(const floatx4*)&p1[i + c * 4];
    const floatx4 d = *(const floatx4*)&xm[i + c * 4];
    floatx4 r;
#pragma unroll
    for (int e = 0; e < 4; e++) r[e] = a[e] + b[e] + d[e];
    *(floatx4*)&out[i + c * 4] = r;
  }
}

// ---------------------------------------------------------------------------
// Fused w1/w2 GEMM + silu-mul. 128x128 DUAL tile, all operands LDS-staged
// with register prefetch. 768 blocks (32 mb x 24 nb), 3 n-stripes/XCD,
// mb outer. LDS 55.3 KB -> 2 blocks/CU. LDS traffic is the binding pipe
// (~26 us floor); read bytes pinned by acc-register budget — structural.
// ---------------------------------------------------------------------------
__global__ __launch_bounds__(256, 2)
void gemm_w12(const bf16* __restrict__ A, const bf16* __restrict__ W1,
              const bf16* __restrict__ W2, bf16* __restrict__ G) {
  __shared__ __align__(16) bf16 As[128 * LDP];
  __shared__ __align__(16) bf16 W1s[128 * LDP];
  __shared__ __align__(16) bf16 W2s[128 * LDP];

  const int L  = blockIdx.x;
  const int j  = L >> 3;                  // 0..95
  const int mb = j / 3;                   // 0..31 (outer per XCD)
  const int nb = (L & 7) * 3 + (j % 3);   // 0..23
  const int m0 = mb * 128, n0 = nb * 128;
  const int K = D_;

  const int tid = threadIdx.x;
  const int lane = tid & 63;
  const int wm = tid >> 7;
  const int wn = (tid >> 6) & 1;
  const int fr = lane & 15;
  const int fk = (lane >> 4) * 8;

  floatx4 acc1[4][4] = {}, acc2[4][4] = {};

  const int ar = tid >> 3;
  const int ac = (tid & 7) * 8;
  const bf16* Aptr  = A  + (long)(m0 + ar) * K + ac;
  const bf16* W1ptr = W1 + (long)(n0 + ar) * K + ac;
  const bf16* W2ptr = W2 + (long)(n0 + ar) * K + ac;
  const long rstep = (long)32 * K;

  bf16x8 apf[4], w1pf[4], w2pf[4];
#pragma unroll
  for (int c = 0; c < 4; c++) { apf[c]  = *(const bf16x8*)(Aptr  + c * rstep);
                                w1pf[c] = *(const bf16x8*)(W1ptr + c * rstep);
                                w2pf[c] = *(const bf16x8*)(W2ptr + c * rstep); }

  const int ns = K >> 6;   // 12
  for (int ks = 0; ks < ns; ks++) {
    __syncthreads();
#pragma unroll
    for (int c = 0; c < 4; c++) { *(bf16x8*)&As[(ar + c * 32) * LDP + ac]  = apf[c];
                                  *(bf16x8*)&W1s[(ar + c * 32) * LDP + ac] = w1pf[c];
                                  *(bf16x8*)&W2s[(ar + c * 32) * LDP + ac] = w2pf[c]; }
    __syncthreads();
    const long koff = (long)((ks + 1 < ns) ? ks + 1 : ks) * 64;
#pragma unroll
    for (int c = 0; c < 4; c++) { apf[c]  = *(const bf16x8*)(Aptr  + koff + c * rstep);
                                  w1pf[c] = *(const bf16x8*)(W1ptr + koff + c * rstep);
                                  w2pf[c] = *(const bf16x8*)(W2ptr + koff + c * rstep); }
#pragma unroll
    for (int kc = 0; kc < 2; kc++) {
      bf16x8 af[4];
#pragma unroll
      for (int i = 0; i < 4; i++) af[i] = *(const bf16x8*)&As[(wm * 64 + i * 16 + fr) * LDP + kc * 32 + fk];
      {
        bf16x8 b1[4];
#pragma unroll
        for (int jj = 0; jj < 4; jj++) b1[jj] = *(const bf16x8*)&W1s[(wn * 64 + jj * 16 + fr) * LDP + kc * 32 + fk];
#pragma unroll
        for (int i = 0; i < 4; i++)
#pragma unroll
          for (int jj = 0; jj < 4; jj++)
            acc1[i][jj] = mfma_bf16(af[i], b1[jj], acc1[i][jj]);
      }
      {
        bf16x8 b2[4];
#pragma unroll
        for (int jj = 0; jj < 4; jj++) b2[jj] = *(const bf16x8*)&W2s[(wn * 64 + jj * 16 + fr) * LDP + kc * 32 + fk];
#pragma unroll
        for (int i = 0; i < 4; i++)
#pragma unroll
          for (int jj = 0; jj < 4; jj++)
            acc2[i][jj] = mfma_bf16(af[i], b2[jj], acc2[i][jj]);
      }
    }
  }

  const int rb = (lane >> 4) * 4;
#pragma unroll
  for (int i = 0; i < 4; i++)
#pragma unroll
    for (int jj = 0; jj < 4; jj++) {
      const int n = n0 + wn * 64 + jj * 16 + fr;
#pragma unroll
      for (int r = 0; r < 4; r++) {
        const int m = m0 + wm * 64 + i * 16 + rb + r;
        const float a1 = acc1[i][jj][r];
        const float a2 = acc2[i][jj][r];
        const float s = a1 / (1.f + exp2f(-a1 * LOG2E));
        G[(long)m * FF_ + n] = (bf16)(s * a2);
      }
    }
}

// ---------------------------------------------------------------------------
// Flash attention, split-K over KV. blockIdx = r*24 + bh (XCD-local K/V).
// Register-prefetch of next round's K/V overlaps global latency with compute.
// ---------------------------------------------------------------------------
__global__ __launch_bounds__(256, 4)
void flash_attn(const bf16* __restrict__ q, const bf16* __restrict__ k,
                const bf16* __restrict__ vtg, float* __restrict__ po,
                float* __restrict__ pm, float* __restrict__ pl) {
  const int gid = blockIdx.x;
  const int bh = gid % 24;
  const int r  = gid / 24;
  int qt, c;
  if (r < 8)       { qt = r; c = 0; }
  else if (r < 24) { qt = 8 + ((r - 8) >> 1); c = (r - 8) & 1; }
  else if (r < 48) { const int u = r - 24; const int d = u / 3; qt = 16 + d; c = u - d * 3; }
  else             { const int u = r - 48; qt = 24 + (u >> 2); c = u & 3; }
  const int b  = bh / H_;
  const int h  = bh % H_;
  const int q0 = qt * 64;
  const int tbeg = c * 8;
  const int tend = (tbeg + 7 < qt) ? tbeg + 7 : qt;

  __shared__ __align__(16) bf16 Qs[64][72];
  __shared__ __align__(16) bf16 Ks[64][72];
  __shared__ __align__(16) bf16 Vt[64][72];
  __shared__ __align__(16) bf16 Ps[4][16][72];

  const int tid = threadIdx.x, lane = tid & 63, w = tid >> 6;
  const int fr = lane & 15, quad = lane >> 4, fk = quad * 8;
  const long base = ((long)b * T_) * D_ + h * HD_;
  const long vbase = (long)bh * HD_ * T_;

  const int srow = tid >> 2, scol = (tid & 3) * 16;
  {
    const long g = base + (long)(q0 + srow) * D_ + scol;
    *(bf16x8*)&Qs[srow][scol]     = *(const bf16x8*)&q[g];
    *(bf16x8*)&Qs[srow][scol + 8] = *(const bf16x8*)&q[g + 8];
  }

  const bf16* kgp = k + base + (long)srow * D_ + scol;
  const bf16* vgp = vtg + vbase + (long)srow * T_ + scol;
  bf16x8 kpf0 = *(const bf16x8*)(kgp + (long)tbeg * 64 * D_);
  bf16x8 kpf1 = *(const bf16x8*)(kgp + (long)tbeg * 64 * D_ + 8);
  bf16x8 vpf0 = *(const bf16x8*)(vgp + tbeg * 64);
  bf16x8 vpf1 = *(const bf16x8*)(vgp + tbeg * 64 + 8);

  float m_st = -1e30f, l_st = 0.f;
  floatx4 o[4] = {};
  const float SC = 0.125f * LOG2E;

  for (int t = tbeg; t <= tend; t++) {
    __syncthreads();
    *(bf16x8*)&Ks[srow][scol]     = kpf0;
    *(bf16x8*)&Ks[srow][scol + 8] = kpf1;
    *(bf16x8*)&Vt[srow][scol]     = vpf0;
    *(bf16x8*)&Vt[srow][scol + 8] = vpf1;
    __syncthreads();
    const int tn = (t + 1 <= tend) ? t + 1 : t;
    kpf0 = *(const bf16x8*)(kgp + (long)tn * 64 * D_);
    kpf1 = *(const bf16x8*)(kgp + (long)tn * 64 * D_ + 8);
    vpf0 = *(const bf16x8*)(vgp + tn * 64);
    vpf1 = *(const bf16x8*)(vgp + tn * 64 + 8);

    floatx4 s[4] = {};
#pragma unroll
    for (int kd = 0; kd < 2; kd++) {
      const bf16x8 bq = *(const bf16x8*)&Qs[w * 16 + fr][kd * 32 + fk];
#pragma unroll
      for (int kt = 0; kt < 4; kt++) {
        const bf16x8 ak = *(const bf16x8*)&Ks[kt * 16 + fr][kd * 32 + fk];
        s[kt] = mfma_bf16(ak, bq, s[kt]);
      }
    }

    if (t == qt) {
      const int qloc = w * 16 + fr;
#pragma unroll
      for (int kt = 0; kt < 4; kt++)
#pragma unroll
        for (int r2 = 0; r2 < 4; r2++) {
          const int kvloc = kt * 16 + quad * 4 + r2;
          s[kt][r2] = (kvloc > qloc) ? -1e30f : s[kt][r2] * SC;
        }
    } else {
#pragma unroll
      for (int kt = 0; kt < 4; kt++)
#pragma unroll
        for (int r2 = 0; r2 < 4; r2++) s[kt][r2] *= SC;
    }

    float mx = -1e30f;
#pragma unroll
    for (int kt = 0; kt < 4; kt++)
#pragma unroll
      for (int r2 = 0; r2 < 4; r2++) mx = fmaxf(mx, s[kt][r2]);
    mx = fmaxf(mx, __shfl_xor(mx, 16));
    mx = fmaxf(mx, __shfl_xor(mx, 32));
    const float mnew  = fmaxf(m_st, mx);
    const float alpha = exp2f(m_st - mnew);
    m_st = mnew;
    float rs = 0.f;
#pragma unroll
    for (int kt = 0; kt < 4; kt++)
#pragma unroll
      for (int r2 = 0; r2 < 4; r2++) {
        const float pv = exp2f(s[kt][r2] - mnew);
        s[kt][r2] = pv;
        rs += pv;
      }
    rs += __shfl_xor(rs, 16);
    rs += __shfl_xor(rs, 32);
    l_st = l_st * alpha + rs;
#pragma unroll
    for (int ht = 0; ht < 4; ht++) o[ht] *= alpha;

#pragma unroll
    for (int kt = 0; kt < 4; kt++) {
      bf16x4 pk;
#pragma unroll
      for (int r2 = 0; r2 < 4; r2++) pk[r2] = (bf16)s[kt][r2];
      *(bf16x4*)&Ps[w][fr][kt * 16 + quad * 4] = pk;
    }

#pragma unroll
    for (int kq = 0; kq < 2; kq++) {
      const bf16x8 bp = *(const bf16x8*)&Ps[w][fr][kq * 32 + fk];
#pragma unroll
      for (int ht = 0; ht < 4; ht++) {
        const bf16x8 av = *(const bf16x8*)&Vt[ht * 16 + fr][kq * 32 + fk];
        o[ht] = mfma_bf16(av, bp, o[ht]);
      }
    }
  }

  const int qq = w * 16 + fr;
  const long pg = (long)gid * 4096 + qq * 64;
#pragma unroll
  for (int ht = 0; ht < 4; ht++)
    *(floatx4*)&po[pg + ht * 16 + quad * 4] = o[ht];
  if (quad == 0) { pm[gid * 64 + qq] = m_st; pl[gid * 64 + qq] = l_st; }
}

// ---------------------------------------------------------------------------
// Combine flash split-K partials: block = (bh, qt), 768 blocks.
// ---------------------------------------------------------------------------
__global__ __launch_bounds__(256)
void flash_comb(const float* __restrict__ po, const float* __restrict__ pm,
                const float* __restrict__ pl, bf16* __restrict__ y) {
  const int bh = blockIdx.x >> 5;
  const int qt = blockIdx.x & 31;
  const int b = bh / H_, h = bh % H_;
  const int nc = (qt >> 3) + 1;
  int bse;
  if      (qt <  8) bse = qt;
  else if (qt < 16) bse = 8  + 2 * (qt - 8);
  else if (qt < 24) bse = 24 + 3 * (qt - 16);
  else              bse = 48 + 4 * (qt - 24);

  const int t = threadIdx.x;
  const int qq = t >> 2, hg = (t & 3) * 16;

  float M = -1e30f;
  for (int c2 = 0; c2 < nc; c2++) M = fmaxf(M, pm[((bse + c2) * 24 + bh) * 64 + qq]);
  float l = 0.f;
  floatx4 o[4] = {};
  for (int c2 = 0; c2 < nc; c2++) {
    const int g = (bse + c2) * 24 + bh;
    const float wgt = exp2f(pm[g * 64 + qq] - M);
    l += wgt * pl[g * 64 + qq];
    const long pg = (long)g * 4096 + qq * 64 + hg;
#pragma unroll
    for (int j = 0; j < 4; j++) {
      const floatx4 t4 = *(const floatx4*)&po[pg + j * 4];
#pragma unroll
      for (int e = 0; e < 4; e++) o[j][e] += wgt * t4[e];
    }
  }
  const float inv = 1.f / l;
  bf16x8 r0, r1;
#pragma unroll
  for (int e = 0; e < 4; e++) {
    r0[e]     = (bf16)(o[0][e] * inv);
    r0[4 + e] = (bf16)(o[1][e] * inv);
    r1[e]     = (bf16)(o[2][e] * inv);
    r1[4 + e] = (bf16)(o[3][e] * inv);
  }
  const long yoff = ((long)b * T_ + qt * 64 + qq) * D_ + h * HD_ + hg;
  *(bf16x8*)&y[yoff]     = r0;
  *(bf16x8*)&y[yoff + 8] = r1;
}

// ---------------------------------------------------------------------------
extern "C" void kernel_launch(void* const* d_in, const int* in_sizes, int n_in,
                              void* d_out, int out_size, void* d_ws, size_t ws_size,
                              hipStream_t stream) {
  const float* x    = (const float*)d_in[0];
  const float* wq   = (const float*)d_in[1];
  const float* wk   = (const float*)d_in[2];
  const float* wv   = (const float*)d_in[3];
  const float* wo   = (const float*)d_in[4];
  const float* w1   = (const float*)d_in[5];
  const float* w2   = (const float*)d_in[6];
  const float* w3   = (const float*)d_in[7];
  const float* anw  = (const float*)d_in[8];
  const float* fnw  = (const float*)d_in[9];
  const float* cosb = (const float*)d_in[10];
  const float* sinb = (const float*)d_in[11];

  char* ws = (char*)d_ws;
  // Layout (bytes), total 88,080,384. Aliasing by lifetime:
  //   po/pm/pl (flash->comb) overlay xm+g region (written later).
  //   w3 partials: p30 over qb+kb (dead after flash), p31 over yb+hn.
  bf16*  wb  = (bf16*)(ws + 0);                // 18,874,368
  bf16*  wqb = wb;
  bf16*  wkb = wb +  589824;
  bf16*  wvb = wb + 1179648;
  bf16*  wob = wb + 1769472;
  bf16*  w1b = wb + 2359296;
  bf16*  w2b = wb + 4718592;
  bf16*  w3b = wb + 7077888;
  bf16*  qb  = (bf16*)(ws + 18874368);
  bf16*  kb  = (bf16*)(ws + 25165824);
  bf16*  vt  = (bf16*)(ws + 31457280);
  bf16*  yb  = (bf16*)(ws + 37748736);
  bf16*  hn  = (bf16*)(ws + 44040192);
  float* xm  = (float*)(ws + 50331648);        // 12,582,912
  bf16*  g   = (bf16*)(ws + 62914560);         // 25,165,824
  float* po  = (float*)(ws + 50331648);        // 31,457,280 (pre-xm/g lifetime)
  float* pm  = (float*)(ws + 81788928);
  float* pl  = (float*)(ws + 82280448);
  float* p30 = (float*)(ws + 18874368);        // over qb+kb
  float* p31 = (float*)(ws + 37748736);        // over yb+hn

  prep_k<<<8704, 256, 0, stream>>>(wq, wk, wv, wo, w1, w2, w3, wb, x, anw, hn);
  gemm_qkv<<<dim3(18, 32), 256, 0, stream>>>(hn, wqb, wkb, wvb, qb, kb, vt, cosb, sinb);
  flash_attn<<<1920, 256, 0, stream>>>(qb, kb, vt, po, pm, pl);
  flash_comb<<<768, 256, 0, stream>>>(po, pm, pl, yb);
  gemm_n64<<<384, 256, 0, stream>>>(yb, wob, xm, x, 768, 768);
  rmsnorm_k<<<4096, 256, 0, stream>>>(xm, fnw, hn);
  gemm_w12<<<768, 256, 0, stream>>>(hn, w1b, w2b, g);
  gemm_w3sk<<<768, 256, 0, stream>>>(g, w3b, p30, p31);
  comb3_k<<<1536, 256, 0, stream>>>(p30, p31, xm, (float*)d_out);
}